// Round 3
// baseline (666.524 us; speedup 1.0000x reference)
//
#include <hip/hip_runtime.h>
#include <hip/hip_bf16.h>

#define NEG_SLOPE 0.1f
#define D1 128
#define D2 256

// bucket = 128 consecutive node ids (shift 7). Edge blocks = 2048 edges.
#define BSH 7
#define NPB 128
#define EPB 2048
#define MAXBUK 1024   // LDS arrays sized for NBUK <= 1024 (N <= 131072)

__device__ __forceinline__ float leaky(float x) { return x >= 0.f ? x : NEG_SLOPE * x; }

__device__ __forceinline__ unsigned short f2bf(float x) {
    union { float f; unsigned int u; } v; v.f = x;
    unsigned int r = (v.u + 0x7FFFu + ((v.u >> 16) & 1u)) >> 16;   // RNE
    return (unsigned short)r;
}

// ---- pass A: per-(block,bucket) histograms for col-keys and row-keys ----
__global__ __launch_bounds__(256) void k_hist(const int* __restrict__ row,
                                              const int* __restrict__ col,
                                              int* __restrict__ T,
                                              int E, int NBLK, int NBUK)
{
    __shared__ int hc[MAXBUK], hr[MAXBUK];
    for (int b = threadIdx.x; b < NBUK; b += 256) { hc[b] = 0; hr[b] = 0; }
    __syncthreads();
    int base = blockIdx.x * EPB;
#pragma unroll
    for (int i = 0; i < 8; i++) {
        int e = base + i * 256 + threadIdx.x;
        if (e < E) {
            atomicAdd(&hc[col[e] >> BSH], 1);
            atomicAdd(&hr[row[e] >> BSH], 1);
        }
    }
    __syncthreads();
    int NT = NBUK * NBLK;
    for (int b = threadIdx.x; b < NBUK; b += 256) {
        T[b * NBLK + blockIdx.x]      = hc[b];
        T[NT + b * NBLK + blockIdx.x] = hr[b];
    }
}

// ---- generic exclusive scan (3 kernels) ----
__global__ __launch_bounds__(256) void k_scan_local(const int* __restrict__ in, int* __restrict__ out,
                                                    int* __restrict__ partials, int n)
{
    __shared__ int s[256];
    int base = blockIdx.x * 2048 + threadIdx.x * 8;
    int v[8]; int sum = 0;
#pragma unroll
    for (int i = 0; i < 8; i++) { v[i] = (base + i < n) ? in[base + i] : 0; sum += v[i]; }
    s[threadIdx.x] = sum;
    __syncthreads();
    for (int off = 1; off < 256; off <<= 1) {
        int t = (threadIdx.x >= off) ? s[threadIdx.x - off] : 0;
        __syncthreads();
        s[threadIdx.x] += t;
        __syncthreads();
    }
    int excl = s[threadIdx.x] - sum;
#pragma unroll
    for (int i = 0; i < 8; i++) { if (base + i < n) { out[base + i] = excl; excl += v[i]; } }
    if (threadIdx.x == 255) partials[blockIdx.x] = s[255];
}

// parallel exclusive scan of up to 1024 block partials (one block)
__global__ __launch_bounds__(1024) void k_scan_partials_par(int* __restrict__ partials, int nb)
{
    __shared__ int s[1024];
    int t = threadIdx.x;
    int v = (t < nb) ? partials[t] : 0;
    s[t] = v;
    __syncthreads();
    for (int off = 1; off < 1024; off <<= 1) {
        int u = (t >= off) ? s[t - off] : 0;
        __syncthreads();
        s[t] += u;
        __syncthreads();
    }
    if (t < nb) partials[t] = s[t] - v;
}

__global__ void k_scan_add(int* __restrict__ out, const int* __restrict__ partials, int n)
{
    int i = blockIdx.x * blockDim.x + threadIdx.x;
    if (i < n) out[i] += partials[i >> 11];
}

// ---- pass B: scatter edges to col-bucket regions (X) and row-bucket regions (Y) ----
// X entry: .x = (c_local<<25) | r   (needs N < 2^25), .y = val bits
// Y entry: .x = r_local, .y = |val| bits
__global__ __launch_bounds__(256) void k_scat(const int* __restrict__ row,
                                              const int* __restrict__ col,
                                              const float* __restrict__ val,
                                              const int* __restrict__ TS,
                                              int2* __restrict__ X, int2* __restrict__ Y,
                                              int E, int NBLK, int NBUK)
{
    __shared__ int oc[MAXBUK], orw[MAXBUK];
    int NT = NBUK * NBLK;
    for (int b = threadIdx.x; b < NBUK; b += 256) {
        oc[b]  = TS[b * NBLK + blockIdx.x];
        orw[b] = TS[NT + b * NBLK + blockIdx.x];
    }
    __syncthreads();
    int base = blockIdx.x * EPB;
#pragma unroll
    for (int i = 0; i < 8; i++) {
        int e = base + i * 256 + threadIdx.x;
        if (e < E) {
            int r = row[e], c = col[e];
            float v = val[e];
            int pc = atomicAdd(&oc[c >> BSH], 1);
            X[pc] = make_int2(((c & (NPB - 1)) << 25) | r, __float_as_int(v));
            int pr = atomicAdd(&orw[r >> BSH], 1);
            Y[pr - E] = make_int2(r & (NPB - 1), __float_as_int(fabsf(v)));
        }
    }
}

// ---- pass C (row): per-row-bucket reduction -> dinv, pv_self ----
__global__ __launch_bounds__(256) void k_rowstats(const int2* __restrict__ Y,
                                                  const int* __restrict__ TS,
                                                  float* __restrict__ dinv,
                                                  float* __restrict__ pv_self,
                                                  int N, int E, int NBLK, int NBUK)
{
    __shared__ float fs[NPB];
    __shared__ int   cn[NPB];
    int t = threadIdx.x;
    if (t < NPB) { fs[t] = 0.f; cn[t] = 0; }
    __syncthreads();
    int NT = NBUK * NBLK;
    int buk = blockIdx.x;
    int s = TS[NT + buk * NBLK];
    int e = (buk == NBUK - 1) ? 2 * E : TS[NT + (buk + 1) * NBLK];
    for (int j = s + t; j < e; j += 256) {
        int2 y = Y[j - E];
        atomicAdd(&fs[y.x], __int_as_float(y.y));
        atomicAdd(&cn[y.x], 1);
    }
    __syncthreads();
    if (t < NPB) {
        int node = buk * NPB + t;
        if (node < N) {
            float as = fs[t];
            float c  = (float)cn[t];
            float am = as / fmaxf(c, 1.f);
            float deg = as + am;
            float di = deg > 0.f ? rsqrtf(deg) : 0.f;
            dinv[node]    = di;
            pv_self[node] = am * di * di;
        }
    }
}

// ---- pass C (col): per-col-bucket node ranking -> col_ptr, srt_rp (r,pv), x1 ----
__global__ __launch_bounds__(256) void k_colfinal(const int2* __restrict__ X,
                                                  const int* __restrict__ TS,
                                                  const float* __restrict__ dinv,
                                                  const float* __restrict__ pv_self,
                                                  int* __restrict__ col_ptr,
                                                  int2* __restrict__ srt_rp,
                                                  float* __restrict__ x1,
                                                  int N, int E, int NBLK, int NBUK)
{
    __shared__ int   hist[NPB];
    __shared__ int   tmp[NPB];
    __shared__ int   rb[NPB];
    __shared__ float xs[NPB];
    __shared__ float dl[NPB];
    int t = threadIdx.x;
    int buk = blockIdx.x;
    int node = buk * NPB + t;
    if (t < NPB) {
        hist[t] = 0; xs[t] = 0.f;
        dl[t] = (node < N) ? dinv[node] : 0.f;
    }
    __syncthreads();
    int s  = TS[buk * NBLK];
    int e2 = (buk == NBUK - 1) ? E : TS[(buk + 1) * NBLK];
    for (int j = s + t; j < e2; j += 256) {
        unsigned xw = (unsigned)X[j].x;
        atomicAdd(&hist[xw >> 25], 1);
    }
    __syncthreads();
    if (t < NPB) tmp[t] = hist[t];
    __syncthreads();
    for (int off = 1; off < NPB; off <<= 1) {
        int u = (t >= off && t < NPB) ? tmp[t - off] : 0;
        __syncthreads();
        if (t < NPB) tmp[t] += u;
        __syncthreads();
    }
    if (t < NPB) {
        int excl = tmp[t] - hist[t];
        rb[t] = s + excl;
        if (node < N) col_ptr[node] = s + excl;
    }
    if (buk == NBUK - 1 && t == 0) col_ptr[N] = E;
    __syncthreads();
    for (int j = s + t; j < e2; j += 256) {
        int2 xx = X[j];
        unsigned xw = (unsigned)xx.x;
        int cl = xw >> 25;
        int r  = (int)(xw & 0x1FFFFFFu);
        float p = __int_as_float(xx.y) * dinv[r] * dl[cl];
        int pos = atomicAdd(&rb[cl], 1);
        srt_rp[pos] = make_int2(r, __float_as_int(p));
        atomicAdd(&xs[cl], p);
    }
    __syncthreads();
    if (t < NPB && node < N) x1[node] = pv_self[node] + xs[t];
}

// ---- F table: F[i,:] = leaky(x1[i]*w1 + b1), N x 128 fp32 ----
__global__ void k_F(const float* __restrict__ x1, const float* __restrict__ w1,
                    const float* __restrict__ b1, float* __restrict__ F, int N)
{
    int i = blockIdx.x * blockDim.x + threadIdx.x;   // over N*64 (2 dims each)
    if (i >= N * 64) return;
    int node = i >> 6, l = i & 63;
    float s = x1[node];
    float2 w = *(const float2*)&w1[l * 2];
    float2 b = *(const float2*)&b1[l * 2];
    float2 f = make_float2(leaky(fmaf(s, w.x, b.x)), leaky(fmaf(s, w.y, b.y)));
    *(float2*)&F[(size_t)i * 2] = f;
}

// ---- conv2 propagate as row-gather over F (prop3 structure, fp32):
// p2[i,:] = pv_self[i]*F[i,:] + sum_j pv_j * F[r_j,:]
__global__ __launch_bounds__(256) void k_prop2g(const int* __restrict__ col_ptr,
                                                const int2* __restrict__ srt_rp,
                                                const float* __restrict__ pv_self,
                                                const float* __restrict__ F,
                                                float* __restrict__ p2, int N)
{
    int node = blockIdx.x * 4 + (threadIdx.x >> 6);
    int lane = threadIdx.x & 63;
    if (node >= N) return;

    float2 fs = *(const float2*)&F[(size_t)node * D1 + lane * 2];
    float ps = pv_self[node];
    float acc0 = ps * fs.x;
    float acc1 = ps * fs.y;

    int j = col_ptr[node], e = col_ptr[node + 1];
    for (; j + 1 < e; j += 2) {
        int2 rp0 = srt_rp[j];
        int2 rp1 = srt_rp[j + 1];
        float2 f0 = *(const float2*)&F[(size_t)rp0.x * D1 + lane * 2];
        float2 f1 = *(const float2*)&F[(size_t)rp1.x * D1 + lane * 2];
        float p0 = __int_as_float(rp0.y);
        float p1 = __int_as_float(rp1.y);
        acc0 += p0 * f0.x;
        acc1 += p0 * f0.y;
        acc0 += p1 * f1.x;
        acc1 += p1 * f1.y;
    }
    if (j < e) {
        int2 rp = srt_rp[j];
        float2 f = *(const float2*)&F[(size_t)rp.x * D1 + lane * 2];
        float p = __int_as_float(rp.y);
        acc0 += p * f.x;
        acc1 += p * f.y;
    }

    *(float2*)&p2[(size_t)node * D1 + lane * 2] = make_float2(acc0, acc1);
}

// ---- conv3 gather propagate over bf16 z, one wave per node, 2 dims per lane ----
__global__ __launch_bounds__(256) void k_prop3_bf16(const int* __restrict__ col_ptr,
                                                    const int2* __restrict__ srt_rp,
                                                    const float* __restrict__ pv_self,
                                                    const unsigned int* __restrict__ zb,
                                                    const float* __restrict__ bias3,
                                                    float* __restrict__ out, int N)
{
    int node = blockIdx.x * 4 + (threadIdx.x >> 6);
    int lane = threadIdx.x & 63;
    if (node >= N) return;

    unsigned int us = zb[(size_t)node * 64 + lane];
    float ps = pv_self[node];
    float acc0 = ps * __uint_as_float(us << 16);
    float acc1 = ps * __uint_as_float(us & 0xFFFF0000u);

    int j = col_ptr[node], e = col_ptr[node + 1];
    for (; j + 1 < e; j += 2) {
        int2 rp0 = srt_rp[j];
        int2 rp1 = srt_rp[j + 1];
        unsigned int u0 = zb[(size_t)rp0.x * 64 + lane];
        unsigned int u1 = zb[(size_t)rp1.x * 64 + lane];
        float p0 = __int_as_float(rp0.y);
        float p1 = __int_as_float(rp1.y);
        acc0 += p0 * __uint_as_float(u0 << 16);
        acc1 += p0 * __uint_as_float(u0 & 0xFFFF0000u);
        acc0 += p1 * __uint_as_float(u1 << 16);
        acc1 += p1 * __uint_as_float(u1 & 0xFFFF0000u);
    }
    if (j < e) {
        int2 rp = srt_rp[j];
        unsigned int u = zb[(size_t)rp.x * 64 + lane];
        float p = __int_as_float(rp.y);
        acc0 += p * __uint_as_float(u << 16);
        acc1 += p * __uint_as_float(u & 0xFFFF0000u);
    }

    float2 b = *(const float2*)&bias3[lane * 2];
    float2 o = make_float2(leaky(acc0 + b.x), leaky(acc1 + b.y));
    *(float2*)&out[(size_t)node * D1 + lane * 2] = o;
}

// ---- tiled fp32 GEMM: C[N x M] = X[N x K] * W^T (+ epilogue), W is (M,K) row-major
template<int K, int M, bool LEAKY, bool X1B, bool BF16OUT>
__global__ __launch_bounds__(256) void k_gemm_t(const float* __restrict__ X,
                                                const float* __restrict__ W,
                                                const float* __restrict__ bvec,
                                                const float* __restrict__ bias,
                                                const float* __restrict__ x1,
                                                void* __restrict__ Cv, int N)
{
    __shared__ float Xs[16][64];   // [k][node]
    __shared__ float Ws[16][64];   // [k][col]

    const int tid = threadIdx.x;
    const int tc  = tid & 15;
    const int tr  = tid >> 4;
    const int n_base = blockIdx.x * 64;
    const int m_base = blockIdx.y * 64;

    float acc[4][4] = {};

    const int ld_row = tid >> 2;
    const int ld_k4  = (tid & 3) * 4;
    const int xnode  = n_base + ld_row;
    const bool xok   = xnode < N;
    const float* Xrow = X + (size_t)xnode * K + ld_k4;
    const float* Wrow = W + (size_t)(m_base + ld_row) * K + ld_k4;

    for (int k0 = 0; k0 < K; k0 += 16) {
        float4 xv = xok ? *(const float4*)(Xrow + k0) : make_float4(0.f, 0.f, 0.f, 0.f);
        float4 wv = *(const float4*)(Wrow + k0);
        __syncthreads();
        Xs[ld_k4 + 0][ld_row] = xv.x;
        Xs[ld_k4 + 1][ld_row] = xv.y;
        Xs[ld_k4 + 2][ld_row] = xv.z;
        Xs[ld_k4 + 3][ld_row] = xv.w;
        Ws[ld_k4 + 0][ld_row] = wv.x;
        Ws[ld_k4 + 1][ld_row] = wv.y;
        Ws[ld_k4 + 2][ld_row] = wv.z;
        Ws[ld_k4 + 3][ld_row] = wv.w;
        __syncthreads();
#pragma unroll
        for (int k = 0; k < 16; k++) {
            float4 a = *(const float4*)&Xs[k][tr * 4];
            float4 b = *(const float4*)&Ws[k][tc * 4];
            acc[0][0] += a.x * b.x; acc[0][1] += a.x * b.y; acc[0][2] += a.x * b.z; acc[0][3] += a.x * b.w;
            acc[1][0] += a.y * b.x; acc[1][1] += a.y * b.y; acc[1][2] += a.y * b.z; acc[1][3] += a.y * b.w;
            acc[2][0] += a.z * b.x; acc[2][1] += a.z * b.y; acc[2][2] += a.z * b.z; acc[2][3] += a.z * b.w;
            acc[3][0] += a.w * b.x; acc[3][1] += a.w * b.y; acc[3][2] += a.w * b.z; acc[3][3] += a.w * b.w;
        }
    }

#pragma unroll
    for (int ii = 0; ii < 4; ii++) {
        int node = n_base + tr * 4 + ii;
        if (node >= N) continue;
        float x1v = X1B ? x1[node] : 0.f;
        float vout[4];
#pragma unroll
        for (int jj = 0; jj < 4; jj++) {
            int m = m_base + tc * 4 + jj;
            float v = acc[ii][jj];
            if (X1B) v += x1v * bvec[m] + bias[m];
            else     v += bvec[m];
            if (LEAKY) v = leaky(v);
            vout[jj] = v;
        }
        if (BF16OUT) {
            ushort4 s4;
            s4.x = f2bf(vout[0]); s4.y = f2bf(vout[1]);
            s4.z = f2bf(vout[2]); s4.w = f2bf(vout[3]);
            *(ushort4*)((unsigned short*)Cv + (size_t)node * M + m_base + tc * 4) = s4;
        } else {
            *(float4*)((float*)Cv + (size_t)node * M + m_base + tc * 4) =
                make_float4(vout[0], vout[1], vout[2], vout[3]);
        }
    }
}

extern "C" void kernel_launch(void* const* d_in, const int* in_sizes, int n_in,
                              void* d_out, int out_size, void* d_ws, size_t ws_size,
                              hipStream_t stream)
{
    const int* ei       = (const int*)d_in[0];     // (2,E) int32
    const float* val    = (const float*)d_in[1];   // (E,)
    const float* w1     = (const float*)d_in[3];   // (128,1)
    const float* b1     = (const float*)d_in[4];   // (128,)
    const float* w2     = (const float*)d_in[5];   // (256,128)
    const float* b2     = (const float*)d_in[6];   // (256,)
    const float* bias2  = (const float*)d_in[7];   // (256,)
    const float* w3     = (const float*)d_in[8];   // (128,256)
    const float* b3     = (const float*)d_in[9];   // (128,)
    const float* bias3  = (const float*)d_in[10];  // (128,)
    float* out = (float*)d_out;

    const int E = in_sizes[1];
    const int N = out_size / D1;
    const int* row = ei;
    const int* col = ei + E;

    const int NBLK = (E + EPB - 1) / EPB;          // edge blocks (782 @ E=1.6M)
    const int NBUK = (N + NPB - 1) >> BSH;         // node buckets (782 @ N=100K)
    const int NT   = NBUK * NBLK;

    // workspace layout
    float* dinv    = (float*)d_ws;                                   // N
    float* pv_self = dinv + N;                                       // N
    float* x1      = pv_self + N;                                    // N
    int*   col_ptr = (int*)(x1 + N);                                 // N+8
    int*   partials= col_ptr + N + 8;                                // 1024
    int2*  srt_rp  = (int2*)(partials + 1024);                       // E int2
    float* p2      = (float*)(srt_rp + (size_t)E);                   // N*128 fp32
    float* h2      = p2 + (size_t)N * D1;                            // N*256 fp32
    // aliases into dead regions:
    int2* X = (int2*)p2;                // E entries (col-bucketed edges)  (dead before k_prop2g writes p2; needs 2E*8 <= N*128*4)
    int2* Y = X + (size_t)E;            // E entries (row-bucketed edges)
    int*  TS = (int*)h2;                // 2*NT scanned table  (dead before k_F writes F)
    int*  T  = TS + (size_t)2 * NT;     // 2*NT raw histograms
    float* F = (float*)h2;              // N*128 fp32 f(x1) table, aliases h2 (dead before gemm1 writes h2)
    unsigned int* zb = (unsigned int*)p2;  // bf16 z aliases dead p2

    const int B = 256;
    const int n2 = 2 * NT;
    const int scan_blocks = (n2 + 2047) / 2048;    // 598 @ default sizes (<= 1024)

    // bucket-sort pipeline: LDS atomics only, zero global atomics, no memsets
    k_hist<<<NBLK, B, 0, stream>>>(row, col, T, E, NBLK, NBUK);
    k_scan_local<<<scan_blocks, 256, 0, stream>>>(T, TS, partials, n2);
    k_scan_partials_par<<<1, 1024, 0, stream>>>(partials, scan_blocks);
    k_scan_add<<<(n2 + B - 1) / B, B, 0, stream>>>(TS, partials, n2);
    k_scat<<<NBLK, B, 0, stream>>>(row, col, val, TS, X, Y, E, NBLK, NBUK);
    k_rowstats<<<NBUK, B, 0, stream>>>(Y, TS, dinv, pv_self, N, E, NBLK, NBUK);
    k_colfinal<<<NBUK, B, 0, stream>>>(X, TS, dinv, pv_self, col_ptr, srt_rp, x1, N, E, NBLK, NBUK);

    // conv2: F table (overwrites dead TS/T region), gather propagate, GEMM 128->256
    k_F<<<(N * 64 + B - 1) / B, B, 0, stream>>>(x1, w1, b1, F, N);
    k_prop2g<<<(N + 3) / 4, 256, 0, stream>>>(col_ptr, srt_rp, pv_self, F, p2, N);
    {
        dim3 grid((N + 63) / 64, D2 / 64);
        k_gemm_t<D1, D2, true, true, false><<<grid, 256, 0, stream>>>(p2, w2, b2, bias2, x1, h2, N);
    }

    // conv3: GEMM 256->128 -> bf16 z, then bf16 gather propagate + fused bias3/leaky
    {
        dim3 grid((N + 63) / 64, D1 / 64);
        k_gemm_t<D2, D1, false, false, true><<<grid, 256, 0, stream>>>(h2, w3, b3, nullptr, nullptr, (void*)zb, N);
    }
    k_prop3_bf16<<<(N + 3) / 4, 256, 0, stream>>>(col_ptr, srt_rp, pv_self, zb, bias3, out, N);
}

// Round 4
// 560.746 us; speedup vs baseline: 1.1886x; 1.1886x over previous
//
#include <hip/hip_runtime.h>
#include <hip/hip_bf16.h>

#define NEG_SLOPE 0.1f
#define D1 128
#define D2 256

// bucket = 128 consecutive node ids (shift 7). Edge blocks = 2048 edges.
#define BSH 7
#define NPB 128
#define EPB 2048
#define MAXBUK 1024   // LDS arrays sized for NBUK <= 1024 (N <= 131072)

__device__ __forceinline__ float leaky(float x) { return x >= 0.f ? x : NEG_SLOPE * x; }

__device__ __forceinline__ unsigned short f2bf(float x) {
    union { float f; unsigned int u; } v; v.f = x;
    unsigned int r = (v.u + 0x7FFFu + ((v.u >> 16) & 1u)) >> 16;   // RNE
    return (unsigned short)r;
}

// ---- pass A: per-(block,bucket) histograms for col-keys and row-keys ----
__global__ __launch_bounds__(256) void k_hist(const int* __restrict__ row,
                                              const int* __restrict__ col,
                                              int* __restrict__ T,
                                              int E, int NBLK, int NBUK)
{
    __shared__ int hc[MAXBUK], hr[MAXBUK];
    for (int b = threadIdx.x; b < NBUK; b += 256) { hc[b] = 0; hr[b] = 0; }
    __syncthreads();
    int base = blockIdx.x * EPB;
#pragma unroll
    for (int i = 0; i < 8; i++) {
        int e = base + i * 256 + threadIdx.x;
        if (e < E) {
            atomicAdd(&hc[col[e] >> BSH], 1);
            atomicAdd(&hr[row[e] >> BSH], 1);
        }
    }
    __syncthreads();
    int NT = NBUK * NBLK;
    for (int b = threadIdx.x; b < NBUK; b += 256) {
        T[b * NBLK + blockIdx.x]      = hc[b];
        T[NT + b * NBLK + blockIdx.x] = hr[b];
    }
}

// ---- generic exclusive scan (3 kernels) ----
__global__ __launch_bounds__(256) void k_scan_local(const int* __restrict__ in, int* __restrict__ out,
                                                    int* __restrict__ partials, int n)
{
    __shared__ int s[256];
    int base = blockIdx.x * 2048 + threadIdx.x * 8;
    int v[8]; int sum = 0;
#pragma unroll
    for (int i = 0; i < 8; i++) { v[i] = (base + i < n) ? in[base + i] : 0; sum += v[i]; }
    s[threadIdx.x] = sum;
    __syncthreads();
    for (int off = 1; off < 256; off <<= 1) {
        int t = (threadIdx.x >= off) ? s[threadIdx.x - off] : 0;
        __syncthreads();
        s[threadIdx.x] += t;
        __syncthreads();
    }
    int excl = s[threadIdx.x] - sum;
#pragma unroll
    for (int i = 0; i < 8; i++) { if (base + i < n) { out[base + i] = excl; excl += v[i]; } }
    if (threadIdx.x == 255) partials[blockIdx.x] = s[255];
}

// parallel exclusive scan of up to 1024 block partials (one block)
__global__ __launch_bounds__(1024) void k_scan_partials_par(int* __restrict__ partials, int nb)
{
    __shared__ int s[1024];
    int t = threadIdx.x;
    int v = (t < nb) ? partials[t] : 0;
    s[t] = v;
    __syncthreads();
    for (int off = 1; off < 1024; off <<= 1) {
        int u = (t >= off) ? s[t - off] : 0;
        __syncthreads();
        s[t] += u;
        __syncthreads();
    }
    if (t < nb) partials[t] = s[t] - v;
}

__global__ void k_scan_add(int* __restrict__ out, const int* __restrict__ partials, int n)
{
    int i = blockIdx.x * blockDim.x + threadIdx.x;
    if (i < n) out[i] += partials[i >> 11];
}

// ---- pass B: scatter edges to col-bucket regions (X) and row-bucket regions (Y) ----
// X entry: .x = (c_local<<25) | r   (needs N < 2^25), .y = val bits
// Y entry: .x = r_local, .y = |val| bits
__global__ __launch_bounds__(256) void k_scat(const int* __restrict__ row,
                                              const int* __restrict__ col,
                                              const float* __restrict__ val,
                                              const int* __restrict__ TS,
                                              int2* __restrict__ X, int2* __restrict__ Y,
                                              int E, int NBLK, int NBUK)
{
    __shared__ int oc[MAXBUK], orw[MAXBUK];
    int NT = NBUK * NBLK;
    for (int b = threadIdx.x; b < NBUK; b += 256) {
        oc[b]  = TS[b * NBLK + blockIdx.x];
        orw[b] = TS[NT + b * NBLK + blockIdx.x];
    }
    __syncthreads();
    int base = blockIdx.x * EPB;
#pragma unroll
    for (int i = 0; i < 8; i++) {
        int e = base + i * 256 + threadIdx.x;
        if (e < E) {
            int r = row[e], c = col[e];
            float v = val[e];
            int pc = atomicAdd(&oc[c >> BSH], 1);
            X[pc] = make_int2(((c & (NPB - 1)) << 25) | r, __float_as_int(v));
            int pr = atomicAdd(&orw[r >> BSH], 1);
            Y[pr - E] = make_int2(r & (NPB - 1), __float_as_int(fabsf(v)));
        }
    }
}

// ---- pass C (row): per-row-bucket reduction -> dinv, pv_self ----
__global__ __launch_bounds__(256) void k_rowstats(const int2* __restrict__ Y,
                                                  const int* __restrict__ TS,
                                                  float* __restrict__ dinv,
                                                  float* __restrict__ pv_self,
                                                  int N, int E, int NBLK, int NBUK)
{
    __shared__ float fs[NPB];
    __shared__ int   cn[NPB];
    int t = threadIdx.x;
    if (t < NPB) { fs[t] = 0.f; cn[t] = 0; }
    __syncthreads();
    int NT = NBUK * NBLK;
    int buk = blockIdx.x;
    int s = TS[NT + buk * NBLK];
    int e = (buk == NBUK - 1) ? 2 * E : TS[NT + (buk + 1) * NBLK];
    for (int j = s + t; j < e; j += 256) {
        int2 y = Y[j - E];
        atomicAdd(&fs[y.x], __int_as_float(y.y));
        atomicAdd(&cn[y.x], 1);
    }
    __syncthreads();
    if (t < NPB) {
        int node = buk * NPB + t;
        if (node < N) {
            float as = fs[t];
            float c  = (float)cn[t];
            float am = as / fmaxf(c, 1.f);
            float deg = as + am;
            float di = deg > 0.f ? rsqrtf(deg) : 0.f;
            dinv[node]    = di;
            pv_self[node] = am * di * di;
        }
    }
}

// ---- pass C (col): per-col-bucket node ranking -> col_ptr, srt_rp (r,pv), x1 ----
__global__ __launch_bounds__(256) void k_colfinal(const int2* __restrict__ X,
                                                  const int* __restrict__ TS,
                                                  const float* __restrict__ dinv,
                                                  const float* __restrict__ pv_self,
                                                  int* __restrict__ col_ptr,
                                                  int2* __restrict__ srt_rp,
                                                  float* __restrict__ x1,
                                                  int N, int E, int NBLK, int NBUK)
{
    __shared__ int   hist[NPB];
    __shared__ int   tmp[NPB];
    __shared__ int   rb[NPB];
    __shared__ float xs[NPB];
    __shared__ float dl[NPB];
    int t = threadIdx.x;
    int buk = blockIdx.x;
    int node = buk * NPB + t;
    if (t < NPB) {
        hist[t] = 0; xs[t] = 0.f;
        dl[t] = (node < N) ? dinv[node] : 0.f;
    }
    __syncthreads();
    int s  = TS[buk * NBLK];
    int e2 = (buk == NBUK - 1) ? E : TS[(buk + 1) * NBLK];
    for (int j = s + t; j < e2; j += 256) {
        unsigned xw = (unsigned)X[j].x;
        atomicAdd(&hist[xw >> 25], 1);
    }
    __syncthreads();
    if (t < NPB) tmp[t] = hist[t];
    __syncthreads();
    for (int off = 1; off < NPB; off <<= 1) {
        int u = (t >= off && t < NPB) ? tmp[t - off] : 0;
        __syncthreads();
        if (t < NPB) tmp[t] += u;
        __syncthreads();
    }
    if (t < NPB) {
        int excl = tmp[t] - hist[t];
        rb[t] = s + excl;
        if (node < N) col_ptr[node] = s + excl;
    }
    if (buk == NBUK - 1 && t == 0) col_ptr[N] = E;
    __syncthreads();
    for (int j = s + t; j < e2; j += 256) {
        int2 xx = X[j];
        unsigned xw = (unsigned)xx.x;
        int cl = xw >> 25;
        int r  = (int)(xw & 0x1FFFFFFu);
        float p = __int_as_float(xx.y) * dinv[r] * dl[cl];
        int pos = atomicAdd(&rb[cl], 1);
        srt_rp[pos] = make_int2(r, __float_as_int(p));
        atomicAdd(&xs[cl], p);
    }
    __syncthreads();
    if (t < NPB && node < N) x1[node] = pv_self[node] + xs[t];
}

// ---- conv2 propagate, broadcast form: one wave per node, 2 dims per lane.
// Chunk 64 edges into registers (pv, x1[row] scalars: 12 B/edge of traffic),
// then wave-uniform loop broadcasting each edge's scalars to all lanes;
// every lane evaluates f_d on the fly (same fma/leaky/order as round-2 k_prop2).
__global__ __launch_bounds__(256) void k_prop2b(const int* __restrict__ col_ptr,
                                                const int2* __restrict__ srt_rp,
                                                const float* __restrict__ pv_self,
                                                const float* __restrict__ x1,
                                                const float* __restrict__ w1,
                                                const float* __restrict__ b1,
                                                float* __restrict__ p2, int N)
{
    int node = blockIdx.x * 4 + (threadIdx.x >> 6);
    int lane = threadIdx.x & 63;
    if (node >= N) return;

    float2 w = *(const float2*)&w1[lane * 2];
    float2 b = *(const float2*)&b1[lane * 2];
    float ps  = pv_self[node];
    float x1n = x1[node];
    float acc0 = ps * leaky(fmaf(x1n, w.x, b.x));
    float acc1 = ps * leaky(fmaf(x1n, w.y, b.y));

    int s = col_ptr[node], e = col_ptr[node + 1];
    for (int base = s; base < e; base += 64) {
        int mc = min(64, e - base);
        float p = 0.f, sv = 0.f;
        if (lane < mc) {
            int2 rp = srt_rp[base + lane];
            p  = __int_as_float(rp.y);
            sv = x1[rp.x];
        }
        for (int k = 0; k < mc; ++k) {
            float pk = __shfl(p, k, 64);
            float sk = __shfl(sv, k, 64);
            acc0 += pk * leaky(fmaf(sk, w.x, b.x));
            acc1 += pk * leaky(fmaf(sk, w.y, b.y));
        }
    }

    *(float2*)&p2[(size_t)node * D1 + lane * 2] = make_float2(acc0, acc1);
}

// ---- conv3 gather propagate over bf16 z, one wave per node, 2 dims per lane ----
__global__ __launch_bounds__(256) void k_prop3_bf16(const int* __restrict__ col_ptr,
                                                    const int2* __restrict__ srt_rp,
                                                    const float* __restrict__ pv_self,
                                                    const unsigned int* __restrict__ zb,
                                                    const float* __restrict__ bias3,
                                                    float* __restrict__ out, int N)
{
    int node = blockIdx.x * 4 + (threadIdx.x >> 6);
    int lane = threadIdx.x & 63;
    if (node >= N) return;

    unsigned int us = zb[(size_t)node * 64 + lane];
    float ps = pv_self[node];
    float acc0 = ps * __uint_as_float(us << 16);
    float acc1 = ps * __uint_as_float(us & 0xFFFF0000u);

    int j = col_ptr[node], e = col_ptr[node + 1];
    for (; j + 1 < e; j += 2) {
        int2 rp0 = srt_rp[j];
        int2 rp1 = srt_rp[j + 1];
        unsigned int u0 = zb[(size_t)rp0.x * 64 + lane];
        unsigned int u1 = zb[(size_t)rp1.x * 64 + lane];
        float p0 = __int_as_float(rp0.y);
        float p1 = __int_as_float(rp1.y);
        acc0 += p0 * __uint_as_float(u0 << 16);
        acc1 += p0 * __uint_as_float(u0 & 0xFFFF0000u);
        acc0 += p1 * __uint_as_float(u1 << 16);
        acc1 += p1 * __uint_as_float(u1 & 0xFFFF0000u);
    }
    if (j < e) {
        int2 rp = srt_rp[j];
        unsigned int u = zb[(size_t)rp.x * 64 + lane];
        float p = __int_as_float(rp.y);
        acc0 += p * __uint_as_float(u << 16);
        acc1 += p * __uint_as_float(u & 0xFFFF0000u);
    }

    float2 b = *(const float2*)&bias3[lane * 2];
    float2 o = make_float2(leaky(acc0 + b.x), leaky(acc1 + b.y));
    *(float2*)&out[(size_t)node * D1 + lane * 2] = o;
}

// ---- tiled fp32 GEMM: C[N x M] = X[N x K] * W^T (+ epilogue), W is (M,K) row-major
template<int K, int M, bool LEAKY, bool X1B, bool BF16OUT>
__global__ __launch_bounds__(256) void k_gemm_t(const float* __restrict__ X,
                                                const float* __restrict__ W,
                                                const float* __restrict__ bvec,
                                                const float* __restrict__ bias,
                                                const float* __restrict__ x1,
                                                void* __restrict__ Cv, int N)
{
    __shared__ float Xs[16][64];   // [k][node]
    __shared__ float Ws[16][64];   // [k][col]

    const int tid = threadIdx.x;
    const int tc  = tid & 15;
    const int tr  = tid >> 4;
    const int n_base = blockIdx.x * 64;
    const int m_base = blockIdx.y * 64;

    float acc[4][4] = {};

    const int ld_row = tid >> 2;
    const int ld_k4  = (tid & 3) * 4;
    const int xnode  = n_base + ld_row;
    const bool xok   = xnode < N;
    const float* Xrow = X + (size_t)xnode * K + ld_k4;
    const float* Wrow = W + (size_t)(m_base + ld_row) * K + ld_k4;

    for (int k0 = 0; k0 < K; k0 += 16) {
        float4 xv = xok ? *(const float4*)(Xrow + k0) : make_float4(0.f, 0.f, 0.f, 0.f);
        float4 wv = *(const float4*)(Wrow + k0);
        __syncthreads();
        Xs[ld_k4 + 0][ld_row] = xv.x;
        Xs[ld_k4 + 1][ld_row] = xv.y;
        Xs[ld_k4 + 2][ld_row] = xv.z;
        Xs[ld_k4 + 3][ld_row] = xv.w;
        Ws[ld_k4 + 0][ld_row] = wv.x;
        Ws[ld_k4 + 1][ld_row] = wv.y;
        Ws[ld_k4 + 2][ld_row] = wv.z;
        Ws[ld_k4 + 3][ld_row] = wv.w;
        __syncthreads();
#pragma unroll
        for (int k = 0; k < 16; k++) {
            float4 a = *(const float4*)&Xs[k][tr * 4];
            float4 b = *(const float4*)&Ws[k][tc * 4];
            acc[0][0] += a.x * b.x; acc[0][1] += a.x * b.y; acc[0][2] += a.x * b.z; acc[0][3] += a.x * b.w;
            acc[1][0] += a.y * b.x; acc[1][1] += a.y * b.y; acc[1][2] += a.y * b.z; acc[1][3] += a.y * b.w;
            acc[2][0] += a.z * b.x; acc[2][1] += a.z * b.y; acc[2][2] += a.z * b.z; acc[2][3] += a.z * b.w;
            acc[3][0] += a.w * b.x; acc[3][1] += a.w * b.y; acc[3][2] += a.w * b.z; acc[3][3] += a.w * b.w;
        }
    }

#pragma unroll
    for (int ii = 0; ii < 4; ii++) {
        int node = n_base + tr * 4 + ii;
        if (node >= N) continue;
        float x1v = X1B ? x1[node] : 0.f;
        float vout[4];
#pragma unroll
        for (int jj = 0; jj < 4; jj++) {
            int m = m_base + tc * 4 + jj;
            float v = acc[ii][jj];
            if (X1B) v += x1v * bvec[m] + bias[m];
            else     v += bvec[m];
            if (LEAKY) v = leaky(v);
            vout[jj] = v;
        }
        if (BF16OUT) {
            ushort4 s4;
            s4.x = f2bf(vout[0]); s4.y = f2bf(vout[1]);
            s4.z = f2bf(vout[2]); s4.w = f2bf(vout[3]);
            *(ushort4*)((unsigned short*)Cv + (size_t)node * M + m_base + tc * 4) = s4;
        } else {
            *(float4*)((float*)Cv + (size_t)node * M + m_base + tc * 4) =
                make_float4(vout[0], vout[1], vout[2], vout[3]);
        }
    }
}

extern "C" void kernel_launch(void* const* d_in, const int* in_sizes, int n_in,
                              void* d_out, int out_size, void* d_ws, size_t ws_size,
                              hipStream_t stream)
{
    const int* ei       = (const int*)d_in[0];     // (2,E) int32
    const float* val    = (const float*)d_in[1];   // (E,)
    const float* w1     = (const float*)d_in[3];   // (128,1)
    const float* b1     = (const float*)d_in[4];   // (128,)
    const float* w2     = (const float*)d_in[5];   // (256,128)
    const float* b2     = (const float*)d_in[6];   // (256,)
    const float* bias2  = (const float*)d_in[7];   // (256,)
    const float* w3     = (const float*)d_in[8];   // (128,256)
    const float* b3     = (const float*)d_in[9];   // (128,)
    const float* bias3  = (const float*)d_in[10];  // (128,)
    float* out = (float*)d_out;

    const int E = in_sizes[1];
    const int N = out_size / D1;
    const int* row = ei;
    const int* col = ei + E;

    const int NBLK = (E + EPB - 1) / EPB;          // edge blocks (782 @ E=1.6M)
    const int NBUK = (N + NPB - 1) >> BSH;         // node buckets (782 @ N=100K)
    const int NT   = NBUK * NBLK;

    // workspace layout
    float* dinv    = (float*)d_ws;                                   // N
    float* pv_self = dinv + N;                                       // N
    float* x1      = pv_self + N;                                    // N
    int*   col_ptr = (int*)(x1 + N);                                 // N+8
    int*   partials= col_ptr + N + 8;                                // 1024
    int2*  srt_rp  = (int2*)(partials + 1024);                       // E int2
    float* p2      = (float*)(srt_rp + (size_t)E);                   // N*128 fp32
    float* h2      = p2 + (size_t)N * D1;                            // N*256 fp32
    // aliases into dead regions:
    int2* X = (int2*)p2;                // E entries (col-bucketed edges)  (dead before k_prop2b writes p2; needs 2E*8 <= N*128*4)
    int2* Y = X + (size_t)E;            // E entries (row-bucketed edges)
    int*  TS = (int*)h2;                // 2*NT scanned table  (dead before gemm1 writes h2)
    int*  T  = TS + (size_t)2 * NT;     // 2*NT raw histograms
    unsigned int* zb = (unsigned int*)p2;  // bf16 z aliases dead p2

    const int B = 256;
    const int n2 = 2 * NT;
    const int scan_blocks = (n2 + 2047) / 2048;    // 598 @ default sizes (<= 1024)

    // bucket-sort pipeline: LDS atomics only, zero global atomics, no memsets
    k_hist<<<NBLK, B, 0, stream>>>(row, col, T, E, NBLK, NBUK);
    k_scan_local<<<scan_blocks, 256, 0, stream>>>(T, TS, partials, n2);
    k_scan_partials_par<<<1, 1024, 0, stream>>>(partials, scan_blocks);
    k_scan_add<<<(n2 + B - 1) / B, B, 0, stream>>>(TS, partials, n2);
    k_scat<<<NBLK, B, 0, stream>>>(row, col, val, TS, X, Y, E, NBLK, NBUK);
    k_rowstats<<<NBUK, B, 0, stream>>>(Y, TS, dinv, pv_self, N, E, NBLK, NBUK);
    k_colfinal<<<NBUK, B, 0, stream>>>(X, TS, dinv, pv_self, col_ptr, srt_rp, x1, N, E, NBLK, NBUK);

    // conv2: broadcast-form propagate (12 B/edge traffic), then GEMM 128->256
    k_prop2b<<<(N + 3) / 4, 256, 0, stream>>>(col_ptr, srt_rp, pv_self, x1, w1, b1, p2, N);
    {
        dim3 grid((N + 63) / 64, D2 / 64);
        k_gemm_t<D1, D2, true, true, false><<<grid, 256, 0, stream>>>(p2, w2, b2, bias2, x1, h2, N);
    }

    // conv3: GEMM 256->128 -> bf16 z, then bf16 gather propagate + fused bias3/leaky
    {
        dim3 grid((N + 63) / 64, D1 / 64);
        k_gemm_t<D2, D1, false, false, true><<<grid, 256, 0, stream>>>(h2, w3, b3, nullptr, nullptr, (void*)zb, N);
    }
    k_prop3_bf16<<<(N + 3) / 4, 256, 0, stream>>>(col_ptr, srt_rp, pv_self, zb, bias3, out, N);
}

// Round 5
// 460.538 us; speedup vs baseline: 1.4473x; 1.2176x over previous
//
#include <hip/hip_runtime.h>
#include <hip/hip_bf16.h>

#define NEG_SLOPE 0.1f
#define D1 128
#define D2 256

// bucket = 128 consecutive node ids (shift 7). Edge blocks = 2048 edges.
#define BSH 7
#define NPB 128
#define EPB 2048
#define MAXBUK 1024   // LDS arrays sized for NBUK <= 1024 (N <= 131072)

__device__ __forceinline__ float leaky(float x) { return x >= 0.f ? x : NEG_SLOPE * x; }

__device__ __forceinline__ unsigned short f2bf(float x) {
    union { float f; unsigned int u; } v; v.f = x;
    unsigned int r = (v.u + 0x7FFFu + ((v.u >> 16) & 1u)) >> 16;   // RNE
    return (unsigned short)r;
}

__device__ __forceinline__ unsigned int pk2bf(float a, float b) {
    return (unsigned int)f2bf(a) | ((unsigned int)f2bf(b) << 16);
}

// ---- pass A: per-(block,bucket) histograms for col-keys and row-keys ----
__global__ __launch_bounds__(256) void k_hist(const int* __restrict__ row,
                                              const int* __restrict__ col,
                                              int* __restrict__ T,
                                              int E, int NBLK, int NBUK)
{
    __shared__ int hc[MAXBUK], hr[MAXBUK];
    for (int b = threadIdx.x; b < NBUK; b += 256) { hc[b] = 0; hr[b] = 0; }
    __syncthreads();
    int base = blockIdx.x * EPB;
#pragma unroll
    for (int i = 0; i < 8; i++) {
        int e = base + i * 256 + threadIdx.x;
        if (e < E) {
            atomicAdd(&hc[col[e] >> BSH], 1);
            atomicAdd(&hr[row[e] >> BSH], 1);
        }
    }
    __syncthreads();
    int NT = NBUK * NBLK;
    for (int b = threadIdx.x; b < NBUK; b += 256) {
        T[b * NBLK + blockIdx.x]      = hc[b];
        T[NT + b * NBLK + blockIdx.x] = hr[b];
    }
}

// ---- generic exclusive scan (3 kernels) ----
__global__ __launch_bounds__(256) void k_scan_local(const int* __restrict__ in, int* __restrict__ out,
                                                    int* __restrict__ partials, int n)
{
    __shared__ int s[256];
    int base = blockIdx.x * 2048 + threadIdx.x * 8;
    int v[8]; int sum = 0;
#pragma unroll
    for (int i = 0; i < 8; i++) { v[i] = (base + i < n) ? in[base + i] : 0; sum += v[i]; }
    s[threadIdx.x] = sum;
    __syncthreads();
    for (int off = 1; off < 256; off <<= 1) {
        int t = (threadIdx.x >= off) ? s[threadIdx.x - off] : 0;
        __syncthreads();
        s[threadIdx.x] += t;
        __syncthreads();
    }
    int excl = s[threadIdx.x] - sum;
#pragma unroll
    for (int i = 0; i < 8; i++) { if (base + i < n) { out[base + i] = excl; excl += v[i]; } }
    if (threadIdx.x == 255) partials[blockIdx.x] = s[255];
}

// parallel exclusive scan of up to 1024 block partials (one block)
__global__ __launch_bounds__(1024) void k_scan_partials_par(int* __restrict__ partials, int nb)
{
    __shared__ int s[1024];
    int t = threadIdx.x;
    int v = (t < nb) ? partials[t] : 0;
    s[t] = v;
    __syncthreads();
    for (int off = 1; off < 1024; off <<= 1) {
        int u = (t >= off) ? s[t - off] : 0;
        __syncthreads();
        s[t] += u;
        __syncthreads();
    }
    if (t < nb) partials[t] = s[t] - v;
}

__global__ void k_scan_add(int* __restrict__ out, const int* __restrict__ partials, int n)
{
    int i = blockIdx.x * blockDim.x + threadIdx.x;
    if (i < n) out[i] += partials[i >> 11];
}

// ---- pass B: scatter edges to col-bucket regions (X) and row-bucket regions (Y) ----
// X entry: .x = (c_local<<25) | r   (needs N < 2^25), .y = val bits
// Y entry: .x = r_local, .y = |val| bits
__global__ __launch_bounds__(256) void k_scat(const int* __restrict__ row,
                                              const int* __restrict__ col,
                                              const float* __restrict__ val,
                                              const int* __restrict__ TS,
                                              int2* __restrict__ X, int2* __restrict__ Y,
                                              int E, int NBLK, int NBUK)
{
    __shared__ int oc[MAXBUK], orw[MAXBUK];
    int NT = NBUK * NBLK;
    for (int b = threadIdx.x; b < NBUK; b += 256) {
        oc[b]  = TS[b * NBLK + blockIdx.x];
        orw[b] = TS[NT + b * NBLK + blockIdx.x];
    }
    __syncthreads();
    int base = blockIdx.x * EPB;
#pragma unroll
    for (int i = 0; i < 8; i++) {
        int e = base + i * 256 + threadIdx.x;
        if (e < E) {
            int r = row[e], c = col[e];
            float v = val[e];
            int pc = atomicAdd(&oc[c >> BSH], 1);
            X[pc] = make_int2(((c & (NPB - 1)) << 25) | r, __float_as_int(v));
            int pr = atomicAdd(&orw[r >> BSH], 1);
            Y[pr - E] = make_int2(r & (NPB - 1), __float_as_int(fabsf(v)));
        }
    }
}

// ---- pass C (row): per-row-bucket reduction -> dinv, pv_self ----
__global__ __launch_bounds__(256) void k_rowstats(const int2* __restrict__ Y,
                                                  const int* __restrict__ TS,
                                                  float* __restrict__ dinv,
                                                  float* __restrict__ pv_self,
                                                  int N, int E, int NBLK, int NBUK)
{
    __shared__ float fs[NPB];
    __shared__ int   cn[NPB];
    int t = threadIdx.x;
    if (t < NPB) { fs[t] = 0.f; cn[t] = 0; }
    __syncthreads();
    int NT = NBUK * NBLK;
    int buk = blockIdx.x;
    int s = TS[NT + buk * NBLK];
    int e = (buk == NBUK - 1) ? 2 * E : TS[NT + (buk + 1) * NBLK];
    for (int j = s + t; j < e; j += 256) {
        int2 y = Y[j - E];
        atomicAdd(&fs[y.x], __int_as_float(y.y));
        atomicAdd(&cn[y.x], 1);
    }
    __syncthreads();
    if (t < NPB) {
        int node = buk * NPB + t;
        if (node < N) {
            float as = fs[t];
            float c  = (float)cn[t];
            float am = as / fmaxf(c, 1.f);
            float deg = as + am;
            float di = deg > 0.f ? rsqrtf(deg) : 0.f;
            dinv[node]    = di;
            pv_self[node] = am * di * di;
        }
    }
}

// ---- pass C (col): per-col-bucket node ranking -> col_ptr, srt_rp (r,pv), x1 ----
__global__ __launch_bounds__(256) void k_colfinal(const int2* __restrict__ X,
                                                  const int* __restrict__ TS,
                                                  const float* __restrict__ dinv,
                                                  const float* __restrict__ pv_self,
                                                  int* __restrict__ col_ptr,
                                                  int2* __restrict__ srt_rp,
                                                  float* __restrict__ x1,
                                                  int N, int E, int NBLK, int NBUK)
{
    __shared__ int   hist[NPB];
    __shared__ int   tmp[NPB];
    __shared__ int   rb[NPB];
    __shared__ float xs[NPB];
    __shared__ float dl[NPB];
    int t = threadIdx.x;
    int buk = blockIdx.x;
    int node = buk * NPB + t;
    if (t < NPB) {
        hist[t] = 0; xs[t] = 0.f;
        dl[t] = (node < N) ? dinv[node] : 0.f;
    }
    __syncthreads();
    int s  = TS[buk * NBLK];
    int e2 = (buk == NBUK - 1) ? E : TS[(buk + 1) * NBLK];
    for (int j = s + t; j < e2; j += 256) {
        unsigned xw = (unsigned)X[j].x;
        atomicAdd(&hist[xw >> 25], 1);
    }
    __syncthreads();
    if (t < NPB) tmp[t] = hist[t];
    __syncthreads();
    for (int off = 1; off < NPB; off <<= 1) {
        int u = (t >= off && t < NPB) ? tmp[t - off] : 0;
        __syncthreads();
        if (t < NPB) tmp[t] += u;
        __syncthreads();
    }
    if (t < NPB) {
        int excl = tmp[t] - hist[t];
        rb[t] = s + excl;
        if (node < N) col_ptr[node] = s + excl;
    }
    if (buk == NBUK - 1 && t == 0) col_ptr[N] = E;
    __syncthreads();
    for (int j = s + t; j < e2; j += 256) {
        int2 xx = X[j];
        unsigned xw = (unsigned)xx.x;
        int cl = xw >> 25;
        int r  = (int)(xw & 0x1FFFFFFu);
        float p = __int_as_float(xx.y) * dinv[r] * dl[cl];
        int pos = atomicAdd(&rb[cl], 1);
        srt_rp[pos] = make_int2(r, __float_as_int(p));
        atomicAdd(&xs[cl], p);
    }
    __syncthreads();
    if (t < NPB && node < N) x1[node] = pv_self[node] + xs[t];
}

// ---- conv2 propagate, broadcast form: one wave per node, 2 dims per lane ----
__global__ __launch_bounds__(256) void k_prop2b(const int* __restrict__ col_ptr,
                                                const int2* __restrict__ srt_rp,
                                                const float* __restrict__ pv_self,
                                                const float* __restrict__ x1,
                                                const float* __restrict__ w1,
                                                const float* __restrict__ b1,
                                                float* __restrict__ p2, int N)
{
    int node = blockIdx.x * 4 + (threadIdx.x >> 6);
    int lane = threadIdx.x & 63;
    if (node >= N) return;

    float2 w = *(const float2*)&w1[lane * 2];
    float2 b = *(const float2*)&b1[lane * 2];
    float ps  = pv_self[node];
    float x1n = x1[node];
    float acc0 = ps * leaky(fmaf(x1n, w.x, b.x));
    float acc1 = ps * leaky(fmaf(x1n, w.y, b.y));

    int s = col_ptr[node], e = col_ptr[node + 1];
    for (int base = s; base < e; base += 64) {
        int mc = min(64, e - base);
        float p = 0.f, sv = 0.f;
        if (lane < mc) {
            int2 rp = srt_rp[base + lane];
            p  = __int_as_float(rp.y);
            sv = x1[rp.x];
        }
        for (int k = 0; k < mc; ++k) {
            float pk = __shfl(p, k, 64);
            float sk = __shfl(sv, k, 64);
            acc0 += pk * leaky(fmaf(sk, w.x, b.x));
            acc1 += pk * leaky(fmaf(sk, w.y, b.y));
        }
    }

    *(float2*)&p2[(size_t)node * D1 + lane * 2] = make_float2(acc0, acc1);
}

// ---- conv3 gather propagate over bf16 z, one wave per node, 2 dims per lane ----
__global__ __launch_bounds__(256) void k_prop3_bf16(const int* __restrict__ col_ptr,
                                                    const int2* __restrict__ srt_rp,
                                                    const float* __restrict__ pv_self,
                                                    const unsigned int* __restrict__ zb,
                                                    const float* __restrict__ bias3,
                                                    float* __restrict__ out, int N)
{
    int node = blockIdx.x * 4 + (threadIdx.x >> 6);
    int lane = threadIdx.x & 63;
    if (node >= N) return;

    unsigned int us = zb[(size_t)node * 64 + lane];
    float ps = pv_self[node];
    float acc0 = ps * __uint_as_float(us << 16);
    float acc1 = ps * __uint_as_float(us & 0xFFFF0000u);

    int j = col_ptr[node], e = col_ptr[node + 1];
    for (; j + 1 < e; j += 2) {
        int2 rp0 = srt_rp[j];
        int2 rp1 = srt_rp[j + 1];
        unsigned int u0 = zb[(size_t)rp0.x * 64 + lane];
        unsigned int u1 = zb[(size_t)rp1.x * 64 + lane];
        float p0 = __int_as_float(rp0.y);
        float p1 = __int_as_float(rp1.y);
        acc0 += p0 * __uint_as_float(u0 << 16);
        acc1 += p0 * __uint_as_float(u0 & 0xFFFF0000u);
        acc0 += p1 * __uint_as_float(u1 << 16);
        acc1 += p1 * __uint_as_float(u1 & 0xFFFF0000u);
    }
    if (j < e) {
        int2 rp = srt_rp[j];
        unsigned int u = zb[(size_t)rp.x * 64 + lane];
        float p = __int_as_float(rp.y);
        acc0 += p * __uint_as_float(u << 16);
        acc1 += p * __uint_as_float(u & 0xFFFF0000u);
    }

    float2 b = *(const float2*)&bias3[lane * 2];
    float2 o = make_float2(leaky(acc0 + b.x), leaky(acc1 + b.y));
    *(float2*)&out[(size_t)node * D1 + lane * 2] = o;
}

// ---- legacy tiled fp32 GEMM (kept as fallback, not instantiated) ----
template<int K, int M, bool LEAKY, bool X1B, bool BF16OUT>
__global__ __launch_bounds__(256) void k_gemm_t(const float* __restrict__ X,
                                                const float* __restrict__ W,
                                                const float* __restrict__ bvec,
                                                const float* __restrict__ bias,
                                                const float* __restrict__ x1,
                                                void* __restrict__ Cv, int N)
{
    __shared__ float Xs[16][64];
    __shared__ float Ws[16][64];

    const int tid = threadIdx.x;
    const int tc  = tid & 15;
    const int tr  = tid >> 4;
    const int n_base = blockIdx.x * 64;
    const int m_base = blockIdx.y * 64;

    float acc[4][4] = {};

    const int ld_row = tid >> 2;
    const int ld_k4  = (tid & 3) * 4;
    const int xnode  = n_base + ld_row;
    const bool xok   = xnode < N;
    const float* Xrow = X + (size_t)xnode * K + ld_k4;
    const float* Wrow = W + (size_t)(m_base + ld_row) * K + ld_k4;

    for (int k0 = 0; k0 < K; k0 += 16) {
        float4 xv = xok ? *(const float4*)(Xrow + k0) : make_float4(0.f, 0.f, 0.f, 0.f);
        float4 wv = *(const float4*)(Wrow + k0);
        __syncthreads();
        Xs[ld_k4 + 0][ld_row] = xv.x;
        Xs[ld_k4 + 1][ld_row] = xv.y;
        Xs[ld_k4 + 2][ld_row] = xv.z;
        Xs[ld_k4 + 3][ld_row] = xv.w;
        Ws[ld_k4 + 0][ld_row] = wv.x;
        Ws[ld_k4 + 1][ld_row] = wv.y;
        Ws[ld_k4 + 2][ld_row] = wv.z;
        Ws[ld_k4 + 3][ld_row] = wv.w;
        __syncthreads();
#pragma unroll
        for (int k = 0; k < 16; k++) {
            float4 a = *(const float4*)&Xs[k][tr * 4];
            float4 b = *(const float4*)&Ws[k][tc * 4];
            acc[0][0] += a.x * b.x; acc[0][1] += a.x * b.y; acc[0][2] += a.x * b.z; acc[0][3] += a.x * b.w;
            acc[1][0] += a.y * b.x; acc[1][1] += a.y * b.y; acc[1][2] += a.y * b.z; acc[1][3] += a.y * b.w;
            acc[2][0] += a.z * b.x; acc[2][1] += a.z * b.y; acc[2][2] += a.z * b.z; acc[2][3] += a.z * b.w;
            acc[3][0] += a.w * b.x; acc[3][1] += a.w * b.y; acc[3][2] += a.w * b.z; acc[3][3] += a.w * b.w;
        }
    }

#pragma unroll
    for (int ii = 0; ii < 4; ii++) {
        int node = n_base + tr * 4 + ii;
        if (node >= N) continue;
        float x1v = X1B ? x1[node] : 0.f;
        float vout[4];
#pragma unroll
        for (int jj = 0; jj < 4; jj++) {
            int m = m_base + tc * 4 + jj;
            float v = acc[ii][jj];
            if (X1B) v += x1v * bvec[m] + bias[m];
            else     v += bvec[m];
            if (LEAKY) v = leaky(v);
            vout[jj] = v;
        }
        if (BF16OUT) {
            ushort4 s4;
            s4.x = f2bf(vout[0]); s4.y = f2bf(vout[1]);
            s4.z = f2bf(vout[2]); s4.w = f2bf(vout[3]);
            *(ushort4*)((unsigned short*)Cv + (size_t)node * M + m_base + tc * 4) = s4;
        } else {
            *(float4*)((float*)Cv + (size_t)node * M + m_base + tc * 4) =
                make_float4(vout[0], vout[1], vout[2], vout[3]);
        }
    }
}

// ---- MFMA bf16 GEMM: C[N x M] = X[N x K] * W^T (+ epilogue), W is (M,K) row-major.
// fp32 inputs converted RNE->bf16 during LDS staging; fp32 accumulate.
// Tile 128(nodes) x 128(cols), 4 waves in 2x2, each wave 64x64 = 4x4 frags of
// v_mfma_f32_16x16x32_bf16. LDS rows padded to 40 ushorts (80 B stride -> 2-way
// bank aliasing, free). A/B frag: lane l reads row (l&15), 8 consecutive k at
// 8*(l>>4); C/D: col = l&15, row = (l>>4)*4 + reg  [m89-verified].
template<int K, int M, bool LEAKY, bool X1B, bool BF16OUT>
__global__ __launch_bounds__(256) void k_gemm_mfma(const float* __restrict__ X,
                                                   const float* __restrict__ W,
                                                   const float* __restrict__ bvec,
                                                   const float* __restrict__ bias,
                                                   const float* __restrict__ x1,
                                                   void* __restrict__ Cv, int N)
{
    typedef __attribute__((ext_vector_type(8))) short short8v;
    typedef __attribute__((ext_vector_type(4))) float f32x4;

    __shared__ unsigned short Al[128 * 40];
    __shared__ unsigned short Bl[128 * 40];

    const int t = threadIdx.x;
    const int n_base = blockIdx.x * 128;
    const int m_base = blockIdx.y * 128;
    const int l  = t & 63, wid = t >> 6;
    const int wr = wid >> 1, wc = wid & 1;
    const int lr = l & 15,  lk = l >> 4;

    f32x4 acc[4][4] = {};

    const int srow  = t >> 1;      // 0..127
    const int shalf = t & 1;       // which 16-float half of the 32-k step
    const bool aok = (n_base + srow) < N;
    const float* pA = X + (size_t)(n_base + srow) * K + shalf * 16;
    const float* pB = W + (size_t)(m_base + srow) * K + shalf * 16;
    unsigned short* wA = &Al[srow * 40 + shalf * 16];
    unsigned short* wB = &Bl[srow * 40 + shalf * 16];

    for (int k0 = 0; k0 < K; k0 += 32) {
        float4 ra0, ra1, ra2, ra3;
        if (aok) {
            ra0 = *(const float4*)(pA + k0);
            ra1 = *(const float4*)(pA + k0 + 4);
            ra2 = *(const float4*)(pA + k0 + 8);
            ra3 = *(const float4*)(pA + k0 + 12);
        } else {
            ra0 = ra1 = ra2 = ra3 = make_float4(0.f, 0.f, 0.f, 0.f);
        }
        float4 rb0 = *(const float4*)(pB + k0);
        float4 rb1 = *(const float4*)(pB + k0 + 4);
        float4 rb2 = *(const float4*)(pB + k0 + 8);
        float4 rb3 = *(const float4*)(pB + k0 + 12);

        __syncthreads();   // previous iteration's frag reads complete
        uint4 ua0 = make_uint4(pk2bf(ra0.x, ra0.y), pk2bf(ra0.z, ra0.w),
                               pk2bf(ra1.x, ra1.y), pk2bf(ra1.z, ra1.w));
        uint4 ua1 = make_uint4(pk2bf(ra2.x, ra2.y), pk2bf(ra2.z, ra2.w),
                               pk2bf(ra3.x, ra3.y), pk2bf(ra3.z, ra3.w));
        uint4 ub0 = make_uint4(pk2bf(rb0.x, rb0.y), pk2bf(rb0.z, rb0.w),
                               pk2bf(rb1.x, rb1.y), pk2bf(rb1.z, rb1.w));
        uint4 ub1 = make_uint4(pk2bf(rb2.x, rb2.y), pk2bf(rb2.z, rb2.w),
                               pk2bf(rb3.x, rb3.y), pk2bf(rb3.z, rb3.w));
        *(uint4*)wA = ua0;  *(uint4*)(wA + 8) = ua1;
        *(uint4*)wB = ub0;  *(uint4*)(wB + 8) = ub1;
        __syncthreads();

        short8v af[4], bf[4];
#pragma unroll
        for (int i = 0; i < 4; i++) {
            af[i] = *(const short8v*)&Al[(wr * 64 + i * 16 + lr) * 40 + lk * 8];
            bf[i] = *(const short8v*)&Bl[(wc * 64 + i * 16 + lr) * 40 + lk * 8];
        }
#pragma unroll
        for (int i = 0; i < 4; i++)
#pragma unroll
            for (int j = 0; j < 4; j++)
                acc[i][j] = __builtin_amdgcn_mfma_f32_16x16x32_bf16(af[i], bf[j], acc[i][j], 0, 0, 0);
    }

#pragma unroll
    for (int i = 0; i < 4; i++) {
#pragma unroll
        for (int j = 0; j < 4; j++) {
            const int mcol = m_base + wc * 64 + j * 16 + lr;
            const float bv = bvec[mcol];
            const float bi = X1B ? bias[mcol] : 0.f;
#pragma unroll
            for (int q = 0; q < 4; q++) {
                int node = n_base + wr * 64 + i * 16 + lk * 4 + q;
                if (node < N) {
                    float v = acc[i][j][q];
                    if (X1B) v += x1[node] * bv + bi;
                    else     v += bv;
                    if (LEAKY) v = leaky(v);
                    if (BF16OUT)
                        ((unsigned short*)Cv)[(size_t)node * M + mcol] = f2bf(v);
                    else
                        ((float*)Cv)[(size_t)node * M + mcol] = v;
                }
            }
        }
    }
}

extern "C" void kernel_launch(void* const* d_in, const int* in_sizes, int n_in,
                              void* d_out, int out_size, void* d_ws, size_t ws_size,
                              hipStream_t stream)
{
    const int* ei       = (const int*)d_in[0];     // (2,E) int32
    const float* val    = (const float*)d_in[1];   // (E,)
    const float* w1     = (const float*)d_in[3];   // (128,1)
    const float* b1     = (const float*)d_in[4];   // (128,)
    const float* w2     = (const float*)d_in[5];   // (256,128)
    const float* b2     = (const float*)d_in[6];   // (256,)
    const float* bias2  = (const float*)d_in[7];   // (256,)
    const float* w3     = (const float*)d_in[8];   // (128,256)
    const float* b3     = (const float*)d_in[9];   // (128,)
    const float* bias3  = (const float*)d_in[10];  // (128,)
    float* out = (float*)d_out;

    const int E = in_sizes[1];
    const int N = out_size / D1;
    const int* row = ei;
    const int* col = ei + E;

    const int NBLK = (E + EPB - 1) / EPB;          // edge blocks (782 @ E=1.6M)
    const int NBUK = (N + NPB - 1) >> BSH;         // node buckets (782 @ N=100K)
    const int NT   = NBUK * NBLK;

    // workspace layout
    float* dinv    = (float*)d_ws;                                   // N
    float* pv_self = dinv + N;                                       // N
    float* x1      = pv_self + N;                                    // N
    int*   col_ptr = (int*)(x1 + N);                                 // N+8
    int*   partials= col_ptr + N + 8;                                // 1024
    int2*  srt_rp  = (int2*)(partials + 1024);                       // E int2
    float* p2      = (float*)(srt_rp + (size_t)E);                   // N*128 fp32
    float* h2      = p2 + (size_t)N * D1;                            // N*256 fp32
    // aliases into dead regions:
    int2* X = (int2*)p2;                // E entries (col-bucketed edges)  (dead before k_prop2b writes p2; needs 2E*8 <= N*128*4)
    int2* Y = X + (size_t)E;            // E entries (row-bucketed edges)
    int*  TS = (int*)h2;                // 2*NT scanned table  (dead before gemm1 writes h2)
    int*  T  = TS + (size_t)2 * NT;     // 2*NT raw histograms
    unsigned int* zb = (unsigned int*)p2;  // bf16 z aliases dead p2

    const int B = 256;
    const int n2 = 2 * NT;
    const int scan_blocks = (n2 + 2047) / 2048;    // 598 @ default sizes (<= 1024)

    // bucket-sort pipeline: LDS atomics only, zero global atomics, no memsets
    k_hist<<<NBLK, B, 0, stream>>>(row, col, T, E, NBLK, NBUK);
    k_scan_local<<<scan_blocks, 256, 0, stream>>>(T, TS, partials, n2);
    k_scan_partials_par<<<1, 1024, 0, stream>>>(partials, scan_blocks);
    k_scan_add<<<(n2 + B - 1) / B, B, 0, stream>>>(TS, partials, n2);
    k_scat<<<NBLK, B, 0, stream>>>(row, col, val, TS, X, Y, E, NBLK, NBUK);
    k_rowstats<<<NBUK, B, 0, stream>>>(Y, TS, dinv, pv_self, N, E, NBLK, NBUK);
    k_colfinal<<<NBUK, B, 0, stream>>>(X, TS, dinv, pv_self, col_ptr, srt_rp, x1, N, E, NBLK, NBUK);

    // conv2: broadcast-form propagate (12 B/edge traffic), then MFMA GEMM 128->256
    k_prop2b<<<(N + 3) / 4, 256, 0, stream>>>(col_ptr, srt_rp, pv_self, x1, w1, b1, p2, N);
    {
        dim3 grid((N + 127) / 128, D2 / 128);
        k_gemm_mfma<D1, D2, true, true, false><<<grid, 256, 0, stream>>>(p2, w2, b2, bias2, x1, h2, N);
    }

    // conv3: MFMA GEMM 256->128 -> bf16 z, then bf16 gather propagate + fused bias3/leaky
    {
        dim3 grid((N + 127) / 128, D1 / 128);
        k_gemm_mfma<D2, D1, false, false, true><<<grid, 256, 0, stream>>>(h2, w3, b3, nullptr, nullptr, (void*)zb, N);
    }
    k_prop3_bf16<<<(N + 3) / 4, 256, 0, stream>>>(col_ptr, srt_rp, pv_self, zb, bias3, out, N);
}

// Round 6
// 428.650 us; speedup vs baseline: 1.5549x; 1.0744x over previous
//
#include <hip/hip_runtime.h>
#include <hip/hip_bf16.h>

#define NEG_SLOPE 0.1f
#define D1 128
#define D2 256

// bucket = 128 consecutive node ids (shift 7). Edge blocks = 2048 edges.
#define BSH 7
#define NPB 128
#define EPB 2048
#define MAXBUK 1024   // LDS arrays sized for NBUK <= 1024 (N <= 131072)

__device__ __forceinline__ float leaky(float x) { return x >= 0.f ? x : NEG_SLOPE * x; }

__device__ __forceinline__ unsigned short f2bf(float x) {
    union { float f; unsigned int u; } v; v.f = x;
    unsigned int r = (v.u + 0x7FFFu + ((v.u >> 16) & 1u)) >> 16;   // RNE
    return (unsigned short)r;
}

__device__ __forceinline__ unsigned int pk2bf(float a, float b) {
    return (unsigned int)f2bf(a) | ((unsigned int)f2bf(b) << 16);
}

// ---- pass A: per-(block,bucket) histograms for col-keys and row-keys ----
__global__ __launch_bounds__(256) void k_hist(const int* __restrict__ row,
                                              const int* __restrict__ col,
                                              int* __restrict__ T,
                                              int E, int NBLK, int NBUK)
{
    __shared__ int hc[MAXBUK], hr[MAXBUK];
    for (int b = threadIdx.x; b < NBUK; b += 256) { hc[b] = 0; hr[b] = 0; }
    __syncthreads();
    int base = blockIdx.x * EPB;
#pragma unroll
    for (int i = 0; i < 8; i++) {
        int e = base + i * 256 + threadIdx.x;
        if (e < E) {
            atomicAdd(&hc[col[e] >> BSH], 1);
            atomicAdd(&hr[row[e] >> BSH], 1);
        }
    }
    __syncthreads();
    int NT = NBUK * NBLK;
    for (int b = threadIdx.x; b < NBUK; b += 256) {
        T[b * NBLK + blockIdx.x]      = hc[b];
        T[NT + b * NBLK + blockIdx.x] = hr[b];
    }
}

// ---- generic exclusive scan (3 kernels) ----
__global__ __launch_bounds__(256) void k_scan_local(const int* __restrict__ in, int* __restrict__ out,
                                                    int* __restrict__ partials, int n)
{
    __shared__ int s[256];
    int base = blockIdx.x * 2048 + threadIdx.x * 8;
    int v[8]; int sum = 0;
#pragma unroll
    for (int i = 0; i < 8; i++) { v[i] = (base + i < n) ? in[base + i] : 0; sum += v[i]; }
    s[threadIdx.x] = sum;
    __syncthreads();
    for (int off = 1; off < 256; off <<= 1) {
        int t = (threadIdx.x >= off) ? s[threadIdx.x - off] : 0;
        __syncthreads();
        s[threadIdx.x] += t;
        __syncthreads();
    }
    int excl = s[threadIdx.x] - sum;
#pragma unroll
    for (int i = 0; i < 8; i++) { if (base + i < n) { out[base + i] = excl; excl += v[i]; } }
    if (threadIdx.x == 255) partials[blockIdx.x] = s[255];
}

// parallel exclusive scan of up to 1024 block partials (one block)
__global__ __launch_bounds__(1024) void k_scan_partials_par(int* __restrict__ partials, int nb)
{
    __shared__ int s[1024];
    int t = threadIdx.x;
    int v = (t < nb) ? partials[t] : 0;
    s[t] = v;
    __syncthreads();
    for (int off = 1; off < 1024; off <<= 1) {
        int u = (t >= off) ? s[t - off] : 0;
        __syncthreads();
        s[t] += u;
        __syncthreads();
    }
    if (t < nb) partials[t] = s[t] - v;
}

__global__ void k_scan_add(int* __restrict__ out, const int* __restrict__ partials, int n)
{
    int i = blockIdx.x * blockDim.x + threadIdx.x;
    if (i < n) out[i] += partials[i >> 11];
}

// ---- pass B: scatter edges to col-bucket regions (X) and row-bucket regions (Y) ----
// X entry: .x = (c_local<<25) | r   (needs N < 2^25), .y = val bits
// Y entry: .x = r_local, .y = |val| bits
__global__ __launch_bounds__(256) void k_scat(const int* __restrict__ row,
                                              const int* __restrict__ col,
                                              const float* __restrict__ val,
                                              const int* __restrict__ TS,
                                              int2* __restrict__ X, int2* __restrict__ Y,
                                              int E, int NBLK, int NBUK)
{
    __shared__ int oc[MAXBUK], orw[MAXBUK];
    int NT = NBUK * NBLK;
    for (int b = threadIdx.x; b < NBUK; b += 256) {
        oc[b]  = TS[b * NBLK + blockIdx.x];
        orw[b] = TS[NT + b * NBLK + blockIdx.x];
    }
    __syncthreads();
    int base = blockIdx.x * EPB;
#pragma unroll
    for (int i = 0; i < 8; i++) {
        int e = base + i * 256 + threadIdx.x;
        if (e < E) {
            int r = row[e], c = col[e];
            float v = val[e];
            int pc = atomicAdd(&oc[c >> BSH], 1);
            X[pc] = make_int2(((c & (NPB - 1)) << 25) | r, __float_as_int(v));
            int pr = atomicAdd(&orw[r >> BSH], 1);
            Y[pr - E] = make_int2(r & (NPB - 1), __float_as_int(fabsf(v)));
        }
    }
}

// ---- pass C (row): per-row-bucket reduction -> dinv, pv_self ----
__global__ __launch_bounds__(256) void k_rowstats(const int2* __restrict__ Y,
                                                  const int* __restrict__ TS,
                                                  float* __restrict__ dinv,
                                                  float* __restrict__ pv_self,
                                                  int N, int E, int NBLK, int NBUK)
{
    __shared__ float fs[NPB];
    __shared__ int   cn[NPB];
    int t = threadIdx.x;
    if (t < NPB) { fs[t] = 0.f; cn[t] = 0; }
    __syncthreads();
    int NT = NBUK * NBLK;
    int buk = blockIdx.x;
    int s = TS[NT + buk * NBLK];
    int e = (buk == NBUK - 1) ? 2 * E : TS[NT + (buk + 1) * NBLK];
    for (int j = s + t; j < e; j += 256) {
        int2 y = Y[j - E];
        atomicAdd(&fs[y.x], __int_as_float(y.y));
        atomicAdd(&cn[y.x], 1);
    }
    __syncthreads();
    if (t < NPB) {
        int node = buk * NPB + t;
        if (node < N) {
            float as = fs[t];
            float c  = (float)cn[t];
            float am = as / fmaxf(c, 1.f);
            float deg = as + am;
            float di = deg > 0.f ? rsqrtf(deg) : 0.f;
            dinv[node]    = di;
            pv_self[node] = am * di * di;
        }
    }
}

// ---- pass C (col): per-col-bucket node ranking -> col_ptr, srt_rp (r,pv), x1 ----
__global__ __launch_bounds__(256) void k_colfinal(const int2* __restrict__ X,
                                                  const int* __restrict__ TS,
                                                  const float* __restrict__ dinv,
                                                  const float* __restrict__ pv_self,
                                                  int* __restrict__ col_ptr,
                                                  int2* __restrict__ srt_rp,
                                                  float* __restrict__ x1,
                                                  int N, int E, int NBLK, int NBUK)
{
    __shared__ int   hist[NPB];
    __shared__ int   tmp[NPB];
    __shared__ int   rb[NPB];
    __shared__ float xs[NPB];
    __shared__ float dl[NPB];
    int t = threadIdx.x;
    int buk = blockIdx.x;
    int node = buk * NPB + t;
    if (t < NPB) {
        hist[t] = 0; xs[t] = 0.f;
        dl[t] = (node < N) ? dinv[node] : 0.f;
    }
    __syncthreads();
    int s  = TS[buk * NBLK];
    int e2 = (buk == NBUK - 1) ? E : TS[(buk + 1) * NBLK];
    for (int j = s + t; j < e2; j += 256) {
        unsigned xw = (unsigned)X[j].x;
        atomicAdd(&hist[xw >> 25], 1);
    }
    __syncthreads();
    if (t < NPB) tmp[t] = hist[t];
    __syncthreads();
    for (int off = 1; off < NPB; off <<= 1) {
        int u = (t >= off && t < NPB) ? tmp[t - off] : 0;
        __syncthreads();
        if (t < NPB) tmp[t] += u;
        __syncthreads();
    }
    if (t < NPB) {
        int excl = tmp[t] - hist[t];
        rb[t] = s + excl;
        if (node < N) col_ptr[node] = s + excl;
    }
    if (buk == NBUK - 1 && t == 0) col_ptr[N] = E;
    __syncthreads();
    for (int j = s + t; j < e2; j += 256) {
        int2 xx = X[j];
        unsigned xw = (unsigned)xx.x;
        int cl = xw >> 25;
        int r  = (int)(xw & 0x1FFFFFFu);
        float p = __int_as_float(xx.y) * dinv[r] * dl[cl];
        int pos = atomicAdd(&rb[cl], 1);
        srt_rp[pos] = make_int2(r, __float_as_int(p));
        atomicAdd(&xs[cl], p);
    }
    __syncthreads();
    if (t < NPB && node < N) x1[node] = pv_self[node] + xs[t];
}

// ---- conv2 propagate, broadcast form: one wave per node, 2 dims per lane.
// Output stored directly as bf16 (RNE) -- identical bits to what the GEMM's
// staging would have produced from fp32.
__global__ __launch_bounds__(256) void k_prop2b(const int* __restrict__ col_ptr,
                                                const int2* __restrict__ srt_rp,
                                                const float* __restrict__ pv_self,
                                                const float* __restrict__ x1,
                                                const float* __restrict__ w1,
                                                const float* __restrict__ b1,
                                                unsigned int* __restrict__ p2b, int N)
{
    int node = blockIdx.x * 4 + (threadIdx.x >> 6);
    int lane = threadIdx.x & 63;
    if (node >= N) return;

    float2 w = *(const float2*)&w1[lane * 2];
    float2 b = *(const float2*)&b1[lane * 2];
    float ps  = pv_self[node];
    float x1n = x1[node];
    float acc0 = ps * leaky(fmaf(x1n, w.x, b.x));
    float acc1 = ps * leaky(fmaf(x1n, w.y, b.y));

    int s = col_ptr[node], e = col_ptr[node + 1];
    for (int base = s; base < e; base += 64) {
        int mc = min(64, e - base);
        float p = 0.f, sv = 0.f;
        if (lane < mc) {
            int2 rp = srt_rp[base + lane];
            p  = __int_as_float(rp.y);
            sv = x1[rp.x];
        }
        for (int k = 0; k < mc; ++k) {
            float pk = __shfl(p, k, 64);
            float sk = __shfl(sv, k, 64);
            acc0 += pk * leaky(fmaf(sk, w.x, b.x));
            acc1 += pk * leaky(fmaf(sk, w.y, b.y));
        }
    }

    p2b[(size_t)node * 64 + lane] = pk2bf(acc0, acc1);
}

// ---- conv3 gather propagate over bf16 z, one wave per node, 2 dims per lane.
// 4-edge unroll: 4 row-loads in flight per iteration (MLP); accumulation stays
// in strict edge order (p0,p1,p2,p3 sequential) -> bitwise-identical result.
__global__ __launch_bounds__(256) void k_prop3_bf16(const int* __restrict__ col_ptr,
                                                    const int2* __restrict__ srt_rp,
                                                    const float* __restrict__ pv_self,
                                                    const unsigned int* __restrict__ zb,
                                                    const float* __restrict__ bias3,
                                                    float* __restrict__ out, int N)
{
    int node = blockIdx.x * 4 + (threadIdx.x >> 6);
    int lane = threadIdx.x & 63;
    if (node >= N) return;

    unsigned int us = zb[(size_t)node * 64 + lane];
    float ps = pv_self[node];
    float acc0 = ps * __uint_as_float(us << 16);
    float acc1 = ps * __uint_as_float(us & 0xFFFF0000u);

    int j = col_ptr[node], e = col_ptr[node + 1];
    for (; j + 3 < e; j += 4) {
        int2 rp0 = srt_rp[j];
        int2 rp1 = srt_rp[j + 1];
        int2 rp2 = srt_rp[j + 2];
        int2 rp3 = srt_rp[j + 3];
        unsigned int u0 = zb[(size_t)rp0.x * 64 + lane];
        unsigned int u1 = zb[(size_t)rp1.x * 64 + lane];
        unsigned int u2 = zb[(size_t)rp2.x * 64 + lane];
        unsigned int u3 = zb[(size_t)rp3.x * 64 + lane];
        float p0 = __int_as_float(rp0.y);
        float p1 = __int_as_float(rp1.y);
        float p2 = __int_as_float(rp2.y);
        float p3 = __int_as_float(rp3.y);
        acc0 += p0 * __uint_as_float(u0 << 16);
        acc1 += p0 * __uint_as_float(u0 & 0xFFFF0000u);
        acc0 += p1 * __uint_as_float(u1 << 16);
        acc1 += p1 * __uint_as_float(u1 & 0xFFFF0000u);
        acc0 += p2 * __uint_as_float(u2 << 16);
        acc1 += p2 * __uint_as_float(u2 & 0xFFFF0000u);
        acc0 += p3 * __uint_as_float(u3 << 16);
        acc1 += p3 * __uint_as_float(u3 & 0xFFFF0000u);
    }
    for (; j < e; ++j) {
        int2 rp = srt_rp[j];
        unsigned int u = zb[(size_t)rp.x * 64 + lane];
        float p = __int_as_float(rp.y);
        acc0 += p * __uint_as_float(u << 16);
        acc1 += p * __uint_as_float(u & 0xFFFF0000u);
    }

    float2 b = *(const float2*)&bias3[lane * 2];
    float2 o = make_float2(leaky(acc0 + b.x), leaky(acc1 + b.y));
    *(float2*)&out[(size_t)node * D1 + lane * 2] = o;
}

// ---- MFMA bf16 GEMM: C[N x M] = X[N x K] * W^T (+ epilogue), W is (M,K) row-major.
// A operand: bf16 in memory if ABF16 (straight copy to LDS), else fp32 converted
// RNE->bf16 during staging. B (weights) always fp32->bf16 staged. fp32 accumulate.
// Tile 128x128, 4 waves 2x2, wave 64x64 = 4x4 frags of v_mfma_f32_16x16x32_bf16.
// LDS rows padded to 40 ushorts (80 B stride -> 2-way bank aliasing, free).
template<int K, int M, bool LEAKY, bool X1B, bool BF16OUT, bool ABF16>
__global__ __launch_bounds__(256) void k_gemm_mfma(const void* __restrict__ Xv,
                                                   const float* __restrict__ W,
                                                   const float* __restrict__ bvec,
                                                   const float* __restrict__ bias,
                                                   const float* __restrict__ x1,
                                                   void* __restrict__ Cv, int N)
{
    typedef __attribute__((ext_vector_type(8))) short short8v;
    typedef __attribute__((ext_vector_type(4))) float f32x4;

    __shared__ unsigned short Al[128 * 40];
    __shared__ unsigned short Bl[128 * 40];

    const int t = threadIdx.x;
    const int n_base = blockIdx.x * 128;
    const int m_base = blockIdx.y * 128;
    const int l  = t & 63, wid = t >> 6;
    const int wr = wid >> 1, wc = wid & 1;
    const int lr = l & 15,  lk = l >> 4;

    f32x4 acc[4][4] = {};

    const int srow  = t >> 1;      // 0..127
    const int shalf = t & 1;       // which 16-elem half of the 32-k step
    const bool aok = (n_base + srow) < N;
    const unsigned short* pA16 = (const unsigned short*)Xv + (size_t)(n_base + srow) * K + shalf * 16;
    const float*          pA32 = (const float*)Xv          + (size_t)(n_base + srow) * K + shalf * 16;
    const float* pB = W + (size_t)(m_base + srow) * K + shalf * 16;
    unsigned short* wA = &Al[srow * 40 + shalf * 16];
    unsigned short* wB = &Bl[srow * 40 + shalf * 16];

    for (int k0 = 0; k0 < K; k0 += 32) {
        uint4 ua0, ua1;
        float4 ra0, ra1, ra2, ra3;
        if constexpr (ABF16) {
            if (aok) {
                ua0 = *(const uint4*)(pA16 + k0);
                ua1 = *(const uint4*)(pA16 + k0 + 8);
            } else {
                ua0 = ua1 = make_uint4(0u, 0u, 0u, 0u);
            }
        } else {
            if (aok) {
                ra0 = *(const float4*)(pA32 + k0);
                ra1 = *(const float4*)(pA32 + k0 + 4);
                ra2 = *(const float4*)(pA32 + k0 + 8);
                ra3 = *(const float4*)(pA32 + k0 + 12);
            } else {
                ra0 = ra1 = ra2 = ra3 = make_float4(0.f, 0.f, 0.f, 0.f);
            }
        }
        float4 rb0 = *(const float4*)(pB + k0);
        float4 rb1 = *(const float4*)(pB + k0 + 4);
        float4 rb2 = *(const float4*)(pB + k0 + 8);
        float4 rb3 = *(const float4*)(pB + k0 + 12);

        __syncthreads();   // previous iteration's frag reads complete
        if constexpr (!ABF16) {
            ua0 = make_uint4(pk2bf(ra0.x, ra0.y), pk2bf(ra0.z, ra0.w),
                             pk2bf(ra1.x, ra1.y), pk2bf(ra1.z, ra1.w));
            ua1 = make_uint4(pk2bf(ra2.x, ra2.y), pk2bf(ra2.z, ra2.w),
                             pk2bf(ra3.x, ra3.y), pk2bf(ra3.z, ra3.w));
        }
        uint4 ub0 = make_uint4(pk2bf(rb0.x, rb0.y), pk2bf(rb0.z, rb0.w),
                               pk2bf(rb1.x, rb1.y), pk2bf(rb1.z, rb1.w));
        uint4 ub1 = make_uint4(pk2bf(rb2.x, rb2.y), pk2bf(rb2.z, rb2.w),
                               pk2bf(rb3.x, rb3.y), pk2bf(rb3.z, rb3.w));
        *(uint4*)wA = ua0;  *(uint4*)(wA + 8) = ua1;
        *(uint4*)wB = ub0;  *(uint4*)(wB + 8) = ub1;
        __syncthreads();

        short8v af[4], bf[4];
#pragma unroll
        for (int i = 0; i < 4; i++) {
            af[i] = *(const short8v*)&Al[(wr * 64 + i * 16 + lr) * 40 + lk * 8];
            bf[i] = *(const short8v*)&Bl[(wc * 64 + i * 16 + lr) * 40 + lk * 8];
        }
#pragma unroll
        for (int i = 0; i < 4; i++)
#pragma unroll
            for (int j = 0; j < 4; j++)
                acc[i][j] = __builtin_amdgcn_mfma_f32_16x16x32_bf16(af[i], bf[j], acc[i][j], 0, 0, 0);
    }

#pragma unroll
    for (int i = 0; i < 4; i++) {
#pragma unroll
        for (int j = 0; j < 4; j++) {
            const int mcol = m_base + wc * 64 + j * 16 + lr;
            const float bv = bvec[mcol];
            const float bi = X1B ? bias[mcol] : 0.f;
#pragma unroll
            for (int q = 0; q < 4; q++) {
                int node = n_base + wr * 64 + i * 16 + lk * 4 + q;
                if (node < N) {
                    float v = acc[i][j][q];
                    if (X1B) v += x1[node] * bv + bi;
                    else     v += bv;
                    if (LEAKY) v = leaky(v);
                    if (BF16OUT)
                        ((unsigned short*)Cv)[(size_t)node * M + mcol] = f2bf(v);
                    else
                        ((float*)Cv)[(size_t)node * M + mcol] = v;
                }
            }
        }
    }
}

extern "C" void kernel_launch(void* const* d_in, const int* in_sizes, int n_in,
                              void* d_out, int out_size, void* d_ws, size_t ws_size,
                              hipStream_t stream)
{
    const int* ei       = (const int*)d_in[0];     // (2,E) int32
    const float* val    = (const float*)d_in[1];   // (E,)
    const float* w1     = (const float*)d_in[3];   // (128,1)
    const float* b1     = (const float*)d_in[4];   // (128,)
    const float* w2     = (const float*)d_in[5];   // (256,128)
    const float* b2     = (const float*)d_in[6];   // (256,)
    const float* bias2  = (const float*)d_in[7];   // (256,)
    const float* w3     = (const float*)d_in[8];   // (128,256)
    const float* b3     = (const float*)d_in[9];   // (128,)
    const float* bias3  = (const float*)d_in[10];  // (128,)
    float* out = (float*)d_out;

    const int E = in_sizes[1];
    const int N = out_size / D1;
    const int* row = ei;
    const int* col = ei + E;

    const int NBLK = (E + EPB - 1) / EPB;          // edge blocks (782 @ E=1.6M)
    const int NBUK = (N + NPB - 1) >> BSH;         // node buckets (782 @ N=100K)
    const int NT   = NBUK * NBLK;

    // workspace layout
    float* dinv    = (float*)d_ws;                                   // N
    float* pv_self = dinv + N;                                       // N
    float* x1      = pv_self + N;                                    // N
    int*   col_ptr = (int*)(x1 + N);                                 // N+8
    int*   partials= col_ptr + N + 8;                                // 1024
    int2*  srt_rp  = (int2*)(partials + 1024);                       // E int2
    unsigned int*   p2b = (unsigned int*)(srt_rp + (size_t)E);       // N*128 bf16 = N*64 uints
    unsigned short* h2b = (unsigned short*)(p2b + (size_t)N * 64);   // N*256 bf16
    // aliases into dead regions:
    int2* X = (int2*)p2b;               // E entries (col-bucketed edges)  (dead before k_prop2b writes p2b; needs 2E*8 <= N*256)
    int2* Y = X + (size_t)E;            // E entries (row-bucketed edges)
    int*  TS = (int*)h2b;               // 2*NT scanned table  (dead before gemm1 writes h2b)
    int*  T  = TS + (size_t)2 * NT;     // 2*NT raw histograms
    unsigned int* zb = (unsigned int*)p2b;  // conv3 bf16 z aliases dead p2b

    const int B = 256;
    const int n2 = 2 * NT;
    const int scan_blocks = (n2 + 2047) / 2048;    // 598 @ default sizes (<= 1024)

    // bucket-sort pipeline: LDS atomics only, zero global atomics, no memsets
    k_hist<<<NBLK, B, 0, stream>>>(row, col, T, E, NBLK, NBUK);
    k_scan_local<<<scan_blocks, 256, 0, stream>>>(T, TS, partials, n2);
    k_scan_partials_par<<<1, 1024, 0, stream>>>(partials, scan_blocks);
    k_scan_add<<<(n2 + B - 1) / B, B, 0, stream>>>(TS, partials, n2);
    k_scat<<<NBLK, B, 0, stream>>>(row, col, val, TS, X, Y, E, NBLK, NBUK);
    k_rowstats<<<NBUK, B, 0, stream>>>(Y, TS, dinv, pv_self, N, E, NBLK, NBUK);
    k_colfinal<<<NBUK, B, 0, stream>>>(X, TS, dinv, pv_self, col_ptr, srt_rp, x1, N, E, NBLK, NBUK);

    // conv2: broadcast-form propagate -> bf16 p2, then MFMA GEMM 128->256 -> bf16 h2
    k_prop2b<<<(N + 3) / 4, 256, 0, stream>>>(col_ptr, srt_rp, pv_self, x1, w1, b1, p2b, N);
    {
        dim3 grid((N + 127) / 128, D2 / 128);
        k_gemm_mfma<D1, D2, true, true, true, true><<<grid, 256, 0, stream>>>(
            (const void*)p2b, w2, b2, bias2, x1, (void*)h2b, N);
    }

    // conv3: MFMA GEMM 256->128 -> bf16 z, then bf16 gather propagate + fused bias3/leaky
    {
        dim3 grid((N + 127) / 128, D1 / 128);
        k_gemm_mfma<D2, D1, false, false, true, true><<<grid, 256, 0, stream>>>(
            (const void*)h2b, w3, b3, nullptr, nullptr, (void*)zb, N);
    }
    k_prop3_bf16<<<(N + 3) / 4, 256, 0, stream>>>(col_ptr, srt_rp, pv_self, zb, bias3, out, N);
}

// Round 7
// 413.721 us; speedup vs baseline: 1.6110x; 1.0361x over previous
//
#include <hip/hip_runtime.h>
#include <hip/hip_bf16.h>

#define NEG_SLOPE 0.1f
#define D1 128
#define D2 256

// bucket = 128 consecutive node ids (shift 7). Edge blocks = 2048 edges.
#define BSH 7
#define NPB 128
#define EPB 2048
#define MAXBUK 1024   // LDS arrays sized for NBUK <= 1024 (N <= 131072)

__device__ __forceinline__ float leaky(float x) { return x >= 0.f ? x : NEG_SLOPE * x; }

__device__ __forceinline__ unsigned short f2bf(float x) {
    union { float f; unsigned int u; } v; v.f = x;
    unsigned int r = (v.u + 0x7FFFu + ((v.u >> 16) & 1u)) >> 16;   // RNE
    return (unsigned short)r;
}

__device__ __forceinline__ unsigned int pk2bf(float a, float b) {
    return (unsigned int)f2bf(a) | ((unsigned int)f2bf(b) << 16);
}

// scanned-table read with the block-partials fixup folded in (replaces k_scan_add)
__device__ __forceinline__ int ts_g(const int* __restrict__ TS,
                                    const int* __restrict__ partials, int idx) {
    return TS[idx] + partials[idx >> 11];
}

// ---- pass A: per-(block,bucket) histograms for col-keys and row-keys ----
__global__ __launch_bounds__(256) void k_hist(const int* __restrict__ row,
                                              const int* __restrict__ col,
                                              int* __restrict__ T,
                                              int E, int NBLK, int NBUK)
{
    __shared__ int hc[MAXBUK], hr[MAXBUK];
    for (int b = threadIdx.x; b < NBUK; b += 256) { hc[b] = 0; hr[b] = 0; }
    __syncthreads();
    int base = blockIdx.x * EPB;
#pragma unroll
    for (int i = 0; i < 8; i++) {
        int e = base + i * 256 + threadIdx.x;
        if (e < E) {
            atomicAdd(&hc[col[e] >> BSH], 1);
            atomicAdd(&hr[row[e] >> BSH], 1);
        }
    }
    __syncthreads();
    int NT = NBUK * NBLK;
    for (int b = threadIdx.x; b < NBUK; b += 256) {
        T[b * NBLK + blockIdx.x]      = hc[b];
        T[NT + b * NBLK + blockIdx.x] = hr[b];
    }
}

// ---- exclusive scan: local pass + partials pass (fixup folded into readers) ----
__global__ __launch_bounds__(256) void k_scan_local(const int* __restrict__ in, int* __restrict__ out,
                                                    int* __restrict__ partials, int n)
{
    __shared__ int s[256];
    int base = blockIdx.x * 2048 + threadIdx.x * 8;
    int v[8]; int sum = 0;
#pragma unroll
    for (int i = 0; i < 8; i++) { v[i] = (base + i < n) ? in[base + i] : 0; sum += v[i]; }
    s[threadIdx.x] = sum;
    __syncthreads();
    for (int off = 1; off < 256; off <<= 1) {
        int t = (threadIdx.x >= off) ? s[threadIdx.x - off] : 0;
        __syncthreads();
        s[threadIdx.x] += t;
        __syncthreads();
    }
    int excl = s[threadIdx.x] - sum;
#pragma unroll
    for (int i = 0; i < 8; i++) { if (base + i < n) { out[base + i] = excl; excl += v[i]; } }
    if (threadIdx.x == 255) partials[blockIdx.x] = s[255];
}

// parallel exclusive scan of up to 1024 block partials (one block)
__global__ __launch_bounds__(1024) void k_scan_partials_par(int* __restrict__ partials, int nb)
{
    __shared__ int s[1024];
    int t = threadIdx.x;
    int v = (t < nb) ? partials[t] : 0;
    s[t] = v;
    __syncthreads();
    for (int off = 1; off < 1024; off <<= 1) {
        int u = (t >= off) ? s[t - off] : 0;
        __syncthreads();
        s[t] += u;
        __syncthreads();
    }
    if (t < nb) partials[t] = s[t] - v;
}

// ---- pass B: scatter edges to col-bucket regions (X) and row-bucket regions (Y) ----
// X entry: .x = (c_local<<25) | r   (needs N < 2^25), .y = val bits
// Y entry: .x = r_local, .y = |val| bits
__global__ __launch_bounds__(256) void k_scat(const int* __restrict__ row,
                                              const int* __restrict__ col,
                                              const float* __restrict__ val,
                                              const int* __restrict__ TS,
                                              const int* __restrict__ partials,
                                              int2* __restrict__ X, int2* __restrict__ Y,
                                              int E, int NBLK, int NBUK)
{
    __shared__ int oc[MAXBUK], orw[MAXBUK];
    int NT = NBUK * NBLK;
    for (int b = threadIdx.x; b < NBUK; b += 256) {
        oc[b]  = ts_g(TS, partials, b * NBLK + blockIdx.x);
        orw[b] = ts_g(TS, partials, NT + b * NBLK + blockIdx.x);
    }
    __syncthreads();
    int base = blockIdx.x * EPB;
#pragma unroll
    for (int i = 0; i < 8; i++) {
        int e = base + i * 256 + threadIdx.x;
        if (e < E) {
            int r = row[e], c = col[e];
            float v = val[e];
            int pc = atomicAdd(&oc[c >> BSH], 1);
            X[pc] = make_int2(((c & (NPB - 1)) << 25) | r, __float_as_int(v));
            int pr = atomicAdd(&orw[r >> BSH], 1);
            Y[pr - E] = make_int2(r & (NPB - 1), __float_as_int(fabsf(v)));
        }
    }
}

// ---- pass C (row): per-row-bucket reduction -> dinv, pv_self ----
__global__ __launch_bounds__(256) void k_rowstats(const int2* __restrict__ Y,
                                                  const int* __restrict__ TS,
                                                  const int* __restrict__ partials,
                                                  float* __restrict__ dinv,
                                                  float* __restrict__ pv_self,
                                                  int N, int E, int NBLK, int NBUK)
{
    __shared__ float fs[NPB];
    __shared__ int   cn[NPB];
    int t = threadIdx.x;
    if (t < NPB) { fs[t] = 0.f; cn[t] = 0; }
    __syncthreads();
    int NT = NBUK * NBLK;
    int buk = blockIdx.x;
    int s = ts_g(TS, partials, NT + buk * NBLK);
    int e = (buk == NBUK - 1) ? 2 * E : ts_g(TS, partials, NT + (buk + 1) * NBLK);
    for (int j = s + t; j < e; j += 256) {
        int2 y = Y[j - E];
        atomicAdd(&fs[y.x], __int_as_float(y.y));
        atomicAdd(&cn[y.x], 1);
    }
    __syncthreads();
    if (t < NPB) {
        int node = buk * NPB + t;
        if (node < N) {
            float as = fs[t];
            float c  = (float)cn[t];
            float am = as / fmaxf(c, 1.f);
            float deg = as + am;
            float di = deg > 0.f ? rsqrtf(deg) : 0.f;
            dinv[node]    = di;
            pv_self[node] = am * di * di;
        }
    }
}

// ---- pass C (col): per-col-bucket node ranking -> col_ptr, srt_rp (r,pv), x1 ----
__global__ __launch_bounds__(256) void k_colfinal(const int2* __restrict__ X,
                                                  const int* __restrict__ TS,
                                                  const int* __restrict__ partials,
                                                  const float* __restrict__ dinv,
                                                  const float* __restrict__ pv_self,
                                                  int* __restrict__ col_ptr,
                                                  int2* __restrict__ srt_rp,
                                                  float* __restrict__ x1,
                                                  int N, int E, int NBLK, int NBUK)
{
    __shared__ int   hist[NPB];
    __shared__ int   tmp[NPB];
    __shared__ int   rb[NPB];
    __shared__ float xs[NPB];
    __shared__ float dl[NPB];
    int t = threadIdx.x;
    int buk = blockIdx.x;
    int node = buk * NPB + t;
    if (t < NPB) {
        hist[t] = 0; xs[t] = 0.f;
        dl[t] = (node < N) ? dinv[node] : 0.f;
    }
    __syncthreads();
    int s  = ts_g(TS, partials, buk * NBLK);
    int e2 = (buk == NBUK - 1) ? E : ts_g(TS, partials, (buk + 1) * NBLK);
    for (int j = s + t; j < e2; j += 256) {
        unsigned xw = (unsigned)X[j].x;
        atomicAdd(&hist[xw >> 25], 1);
    }
    __syncthreads();
    if (t < NPB) tmp[t] = hist[t];
    __syncthreads();
    for (int off = 1; off < NPB; off <<= 1) {
        int u = (t >= off && t < NPB) ? tmp[t - off] : 0;
        __syncthreads();
        if (t < NPB) tmp[t] += u;
        __syncthreads();
    }
    if (t < NPB) {
        int excl = tmp[t] - hist[t];
        rb[t] = s + excl;
        if (node < N) col_ptr[node] = s + excl;
    }
    if (buk == NBUK - 1 && t == 0) col_ptr[N] = E;
    __syncthreads();
    for (int j = s + t; j < e2; j += 256) {
        int2 xx = X[j];
        unsigned xw = (unsigned)xx.x;
        int cl = xw >> 25;
        int r  = (int)(xw & 0x1FFFFFFu);
        float p = __int_as_float(xx.y) * dinv[r] * dl[cl];
        int pos = atomicAdd(&rb[cl], 1);
        srt_rp[pos] = make_int2(r, __float_as_int(p));
        atomicAdd(&xs[cl], p);
    }
    __syncthreads();
    if (t < NPB && node < N) x1[node] = pv_self[node] + xs[t];
}

// ---- conv2 propagate, broadcast form: one wave per node, 2 dims per lane.
// Output stored directly as bf16 (RNE).
__global__ __launch_bounds__(256) void k_prop2b(const int* __restrict__ col_ptr,
                                                const int2* __restrict__ srt_rp,
                                                const float* __restrict__ pv_self,
                                                const float* __restrict__ x1,
                                                const float* __restrict__ w1,
                                                const float* __restrict__ b1,
                                                unsigned int* __restrict__ p2b, int N)
{
    int node = blockIdx.x * 4 + (threadIdx.x >> 6);
    int lane = threadIdx.x & 63;
    if (node >= N) return;

    float2 w = *(const float2*)&w1[lane * 2];
    float2 b = *(const float2*)&b1[lane * 2];
    float ps  = pv_self[node];
    float x1n = x1[node];
    float acc0 = ps * leaky(fmaf(x1n, w.x, b.x));
    float acc1 = ps * leaky(fmaf(x1n, w.y, b.y));

    int s = col_ptr[node], e = col_ptr[node + 1];
    for (int base = s; base < e; base += 64) {
        int mc = min(64, e - base);
        float p = 0.f, sv = 0.f;
        if (lane < mc) {
            int2 rp = srt_rp[base + lane];
            p  = __int_as_float(rp.y);
            sv = x1[rp.x];
        }
        for (int k = 0; k < mc; ++k) {
            float pk = __shfl(p, k, 64);
            float sk = __shfl(sv, k, 64);
            acc0 += pk * leaky(fmaf(sk, w.x, b.x));
            acc1 += pk * leaky(fmaf(sk, w.y, b.y));
        }
    }

    p2b[(size_t)node * 64 + lane] = pk2bf(acc0, acc1);
}

// ---- conv3 gather propagate over bf16 z, one wave per node, 4-edge unroll ----
__global__ __launch_bounds__(256) void k_prop3_bf16(const int* __restrict__ col_ptr,
                                                    const int2* __restrict__ srt_rp,
                                                    const float* __restrict__ pv_self,
                                                    const unsigned int* __restrict__ zb,
                                                    const float* __restrict__ bias3,
                                                    float* __restrict__ out, int N)
{
    int node = blockIdx.x * 4 + (threadIdx.x >> 6);
    int lane = threadIdx.x & 63;
    if (node >= N) return;

    unsigned int us = zb[(size_t)node * 64 + lane];
    float ps = pv_self[node];
    float acc0 = ps * __uint_as_float(us << 16);
    float acc1 = ps * __uint_as_float(us & 0xFFFF0000u);

    int j = col_ptr[node], e = col_ptr[node + 1];
    for (; j + 3 < e; j += 4) {
        int2 rp0 = srt_rp[j];
        int2 rp1 = srt_rp[j + 1];
        int2 rp2 = srt_rp[j + 2];
        int2 rp3 = srt_rp[j + 3];
        unsigned int u0 = zb[(size_t)rp0.x * 64 + lane];
        unsigned int u1 = zb[(size_t)rp1.x * 64 + lane];
        unsigned int u2 = zb[(size_t)rp2.x * 64 + lane];
        unsigned int u3 = zb[(size_t)rp3.x * 64 + lane];
        float p0 = __int_as_float(rp0.y);
        float p1 = __int_as_float(rp1.y);
        float p2 = __int_as_float(rp2.y);
        float p3 = __int_as_float(rp3.y);
        acc0 += p0 * __uint_as_float(u0 << 16);
        acc1 += p0 * __uint_as_float(u0 & 0xFFFF0000u);
        acc0 += p1 * __uint_as_float(u1 << 16);
        acc1 += p1 * __uint_as_float(u1 & 0xFFFF0000u);
        acc0 += p2 * __uint_as_float(u2 << 16);
        acc1 += p2 * __uint_as_float(u2 & 0xFFFF0000u);
        acc0 += p3 * __uint_as_float(u3 << 16);
        acc1 += p3 * __uint_as_float(u3 & 0xFFFF0000u);
    }
    for (; j < e; ++j) {
        int2 rp = srt_rp[j];
        unsigned int u = zb[(size_t)rp.x * 64 + lane];
        float p = __int_as_float(rp.y);
        acc0 += p * __uint_as_float(u << 16);
        acc1 += p * __uint_as_float(u & 0xFFFF0000u);
    }

    float2 b = *(const float2*)&bias3[lane * 2];
    float2 o = make_float2(leaky(acc0 + b.x), leaky(acc1 + b.y));
    *(float2*)&out[(size_t)node * D1 + lane * 2] = o;
}

// ---- fused MFMA GEMM chain: per 64-node tile,
//   phase 1: H(64x256 bf16, LDS) = f2bf(leaky(P@w2^T + x1*b2 + bias2))
//   phase 2: zb = f2bf(H@w3^T + b3)
// H goes through the SAME f2bf at the same point it previously hit HBM ->
// bitwise-identical to the unfused gemm1+gemm2 pair. zb may alias p2b: each
// block reads only its own 64 p2b rows (phase 1, fully consumed) before
// writing the same-extent zb rows (phase 2); no cross-block row sharing.
__global__ __launch_bounds__(256) void k_gemm_fused(const unsigned int* __restrict__ p2b,
                                                    const float* __restrict__ w2,
                                                    const float* __restrict__ b2,
                                                    const float* __restrict__ bias2,
                                                    const float* __restrict__ w3,
                                                    const float* __restrict__ b3,
                                                    const float* __restrict__ x1,
                                                    unsigned short* __restrict__ zb,
                                                    int N)
{
    typedef __attribute__((ext_vector_type(8))) short short8v;
    typedef __attribute__((ext_vector_type(4))) float f32x4;

    __shared__ unsigned short Al[64 * 40];    // A 32-k slice (bf16), 5 KB
    __shared__ unsigned short Bl[256 * 40];   // B 32-k slice (bf16), 20 KB
    __shared__ unsigned short H[64 * 264];    // h2 tile (bf16), 33 KB

    const int t = threadIdx.x;
    const int n_base = blockIdx.x * 64;
    const int l  = t & 63, wid = t >> 6;     // 4 waves
    const int lr = l & 15,  lk = l >> 4;

    // ---------- phase 1: acc1 = P(64x128) @ w2^T -> 64 x 256, wave owns 64 cols
    f32x4 acc1[4][4] = {};
    {
        const int arow = t >> 2, ach = t & 3;          // A: 4 threads/row, uint4 each
        const bool aok = (n_base + arow) < N;
        for (int k0 = 0; k0 < D1; k0 += 32) {
            uint4 ua = make_uint4(0u, 0u, 0u, 0u);
            if (aok) ua = *(const uint4*)&p2b[(size_t)(n_base + arow) * 64 + (k0 >> 1) + ach * 4];
            // B: thread t stages w2 row t (32 fp32 -> bf16)
            const float* pw = w2 + (size_t)t * D1 + k0;
            float4 c0 = *(const float4*)(pw);
            float4 c1 = *(const float4*)(pw + 4);
            float4 c2 = *(const float4*)(pw + 8);
            float4 c3 = *(const float4*)(pw + 12);
            float4 c4 = *(const float4*)(pw + 16);
            float4 c5 = *(const float4*)(pw + 20);
            float4 c6 = *(const float4*)(pw + 24);
            float4 c7 = *(const float4*)(pw + 28);
            __syncthreads();   // previous step's frag reads complete
            *(uint4*)&Al[arow * 40 + ach * 8] = ua;
            uint4 u0 = make_uint4(pk2bf(c0.x, c0.y), pk2bf(c0.z, c0.w),
                                  pk2bf(c1.x, c1.y), pk2bf(c1.z, c1.w));
            uint4 u1 = make_uint4(pk2bf(c2.x, c2.y), pk2bf(c2.z, c2.w),
                                  pk2bf(c3.x, c3.y), pk2bf(c3.z, c3.w));
            uint4 u2 = make_uint4(pk2bf(c4.x, c4.y), pk2bf(c4.z, c4.w),
                                  pk2bf(c5.x, c5.y), pk2bf(c5.z, c5.w));
            uint4 u3 = make_uint4(pk2bf(c6.x, c6.y), pk2bf(c6.z, c6.w),
                                  pk2bf(c7.x, c7.y), pk2bf(c7.z, c7.w));
            *(uint4*)&Bl[t * 40 + 0]  = u0;
            *(uint4*)&Bl[t * 40 + 8]  = u1;
            *(uint4*)&Bl[t * 40 + 16] = u2;
            *(uint4*)&Bl[t * 40 + 24] = u3;
            __syncthreads();

            short8v af[4], bf[4];
#pragma unroll
            for (int i = 0; i < 4; i++) {
                af[i] = *(const short8v*)&Al[(i * 16 + lr) * 40 + lk * 8];
                bf[i] = *(const short8v*)&Bl[(wid * 64 + i * 16 + lr) * 40 + lk * 8];
            }
#pragma unroll
            for (int i = 0; i < 4; i++)
#pragma unroll
                for (int j = 0; j < 4; j++)
                    acc1[i][j] = __builtin_amdgcn_mfma_f32_16x16x32_bf16(af[i], bf[j], acc1[i][j], 0, 0, 0);
        }
    }

    // ---------- epilogue 1 -> H (LDS, bf16)
    {
        float xv[4][4];
#pragma unroll
        for (int i = 0; i < 4; i++)
#pragma unroll
            for (int q = 0; q < 4; q++) {
                int node = n_base + i * 16 + lk * 4 + q;
                xv[i][q] = (node < N) ? x1[node] : 0.f;
            }
#pragma unroll
        for (int j = 0; j < 4; j++) {
            const int col = wid * 64 + j * 16 + lr;
            const float bv = b2[col];
            const float bi = bias2[col];
#pragma unroll
            for (int i = 0; i < 4; i++)
#pragma unroll
                for (int q = 0; q < 4; q++) {
                    int rloc = i * 16 + lk * 4 + q;
                    float v = acc1[i][j][q] + xv[i][q] * bv + bi;
                    H[rloc * 264 + col] = ((n_base + rloc) < N) ? f2bf(leaky(v)) : (unsigned short)0;
                }
        }
    }
    __syncthreads();   // H complete; phase-1 Al/Bl frag reads long done

    // ---------- phase 2: acc2 = H(64x256) @ w3^T -> 64 x 128, wave owns 32 cols
    f32x4 acc2[4][2] = {};
    {
        const int m = t >> 1, hf = t & 1;   // w3: 2 threads/row, 16 k each
        for (int k0 = 0; k0 < D2; k0 += 32) {
            const float* pw = w3 + (size_t)m * D2 + k0 + hf * 16;
            float4 c0 = *(const float4*)(pw);
            float4 c1 = *(const float4*)(pw + 4);
            float4 c2 = *(const float4*)(pw + 8);
            float4 c3 = *(const float4*)(pw + 12);
            __syncthreads();   // previous step's Bl frag reads complete
            uint4 u0 = make_uint4(pk2bf(c0.x, c0.y), pk2bf(c0.z, c0.w),
                                  pk2bf(c1.x, c1.y), pk2bf(c1.z, c1.w));
            uint4 u1 = make_uint4(pk2bf(c2.x, c2.y), pk2bf(c2.z, c2.w),
                                  pk2bf(c3.x, c3.y), pk2bf(c3.z, c3.w));
            *(uint4*)&Bl[m * 40 + hf * 16 + 0] = u0;
            *(uint4*)&Bl[m * 40 + hf * 16 + 8] = u1;
            __syncthreads();

            short8v af[4], bf[2];
#pragma unroll
            for (int i = 0; i < 4; i++)
                af[i] = *(const short8v*)&H[(i * 16 + lr) * 264 + k0 + lk * 8];
#pragma unroll
            for (int j = 0; j < 2; j++)
                bf[j] = *(const short8v*)&Bl[(wid * 32 + j * 16 + lr) * 40 + lk * 8];
#pragma unroll
            for (int i = 0; i < 4; i++)
#pragma unroll
                for (int j = 0; j < 2; j++)
                    acc2[i][j] = __builtin_amdgcn_mfma_f32_16x16x32_bf16(af[i], bf[j], acc2[i][j], 0, 0, 0);
        }
    }

    // ---------- epilogue 2 -> zb (global, bf16)
#pragma unroll
    for (int j = 0; j < 2; j++) {
        const int col = wid * 32 + j * 16 + lr;
        const float bv = b3[col];
#pragma unroll
        for (int i = 0; i < 4; i++)
#pragma unroll
            for (int q = 0; q < 4; q++) {
                int node = n_base + i * 16 + lk * 4 + q;
                if (node < N)
                    zb[(size_t)node * D1 + col] = f2bf(acc2[i][j][q] + bv);
            }
    }
}

extern "C" void kernel_launch(void* const* d_in, const int* in_sizes, int n_in,
                              void* d_out, int out_size, void* d_ws, size_t ws_size,
                              hipStream_t stream)
{
    const int* ei       = (const int*)d_in[0];     // (2,E) int32
    const float* val    = (const float*)d_in[1];   // (E,)
    const float* w1     = (const float*)d_in[3];   // (128,1)
    const float* b1     = (const float*)d_in[4];   // (128,)
    const float* w2     = (const float*)d_in[5];   // (256,128)
    const float* b2     = (const float*)d_in[6];   // (256,)
    const float* bias2  = (const float*)d_in[7];   // (256,)
    const float* w3     = (const float*)d_in[8];   // (128,256)
    const float* b3     = (const float*)d_in[9];   // (128,)
    const float* bias3  = (const float*)d_in[10];  // (128,)
    float* out = (float*)d_out;

    const int E = in_sizes[1];
    const int N = out_size / D1;
    const int* row = ei;
    const int* col = ei + E;

    const int NBLK = (E + EPB - 1) / EPB;          // edge blocks (782 @ E=1.6M)
    const int NBUK = (N + NPB - 1) >> BSH;         // node buckets (782 @ N=100K)
    const int NT   = NBUK * NBLK;

    // workspace layout
    float* dinv    = (float*)d_ws;                                   // N
    float* pv_self = dinv + N;                                       // N
    float* x1      = pv_self + N;                                    // N
    int*   col_ptr = (int*)(x1 + N);                                 // N+8
    int*   partials= col_ptr + N + 8;                                // 1024
    int2*  srt_rp  = (int2*)(partials + 1024);                       // E int2
    unsigned int* p2b = (unsigned int*)(srt_rp + (size_t)E);         // N*64 uints (bf16 p2)
    int*   TS      = (int*)(p2b + (size_t)N * 64);                   // 2*NT scanned table
    int*   T       = TS + (size_t)2 * NT;                            // 2*NT raw histograms
    int2*  Y       = (int2*)(T + (size_t)2 * NT);                    // E (row-bucketed edges)
    // aliases:
    int2* X = (int2*)p2b;                    // E entries; dead before k_prop2b writes p2b (E*8 <= N*256)
    unsigned short* zb = (unsigned short*)p2b;  // fused-GEMM z out; per-block self-alias with p2b is safe

    const int B = 256;
    const int n2 = 2 * NT;
    const int scan_blocks = (n2 + 2047) / 2048;    // 598 @ default sizes (<= 1024)

    // bucket-sort pipeline: LDS atomics only, zero global atomics, no memsets
    k_hist<<<NBLK, B, 0, stream>>>(row, col, T, E, NBLK, NBUK);
    k_scan_local<<<scan_blocks, 256, 0, stream>>>(T, TS, partials, n2);
    k_scan_partials_par<<<1, 1024, 0, stream>>>(partials, scan_blocks);
    k_scat<<<NBLK, B, 0, stream>>>(row, col, val, TS, partials, X, Y, E, NBLK, NBUK);
    k_rowstats<<<NBUK, B, 0, stream>>>(Y, TS, partials, dinv, pv_self, N, E, NBLK, NBUK);
    k_colfinal<<<NBUK, B, 0, stream>>>(X, TS, partials, dinv, pv_self, col_ptr, srt_rp, x1, N, E, NBLK, NBUK);

    // conv2 propagate -> bf16 p2, then fused MFMA chain p2 -> h2(LDS) -> z
    k_prop2b<<<(N + 3) / 4, 256, 0, stream>>>(col_ptr, srt_rp, pv_self, x1, w1, b1, p2b, N);
    k_gemm_fused<<<(N + 63) / 64, 256, 0, stream>>>(p2b, w2, b2, bias2, w3, b3, x1, zb, N);

    // conv3 gather propagate + fused bias3/leaky
    k_prop3_bf16<<<(N + 3) / 4, 256, 0, stream>>>(col_ptr, srt_rp, pv_self, (const unsigned int*)zb, bias3, out, N);
}

// Round 8
// 368.738 us; speedup vs baseline: 1.8076x; 1.1220x over previous
//
#include <hip/hip_runtime.h>
#include <hip/hip_bf16.h>

#define NEG_SLOPE 0.1f
#define D1 128
#define D2 256

// bucket = 128 consecutive node ids (shift 7). Edge blocks = 2048 edges.
#define BSH 7
#define NPB 128
#define EPB 2048
#define MAXBUK 1024   // LDS arrays sized for NBUK <= 1024 (N <= 131072)

__device__ __forceinline__ float leaky(float x) { return x >= 0.f ? x : NEG_SLOPE * x; }

__device__ __forceinline__ unsigned short f2bf(float x) {
    union { float f; unsigned int u; } v; v.f = x;
    unsigned int r = (v.u + 0x7FFFu + ((v.u >> 16) & 1u)) >> 16;   // RNE
    return (unsigned short)r;
}

__device__ __forceinline__ unsigned int pk2bf(float a, float b) {
    return (unsigned int)f2bf(a) | ((unsigned int)f2bf(b) << 16);
}

// scanned-table read with the block-partials fixup folded in (replaces k_scan_add)
__device__ __forceinline__ int ts_g(const int* __restrict__ TS,
                                    const int* __restrict__ partials, int idx) {
    return TS[idx] + partials[idx >> 11];
}

// ---- pass A: per-(block,bucket) histograms for col-keys and row-keys ----
__global__ __launch_bounds__(256) void k_hist(const int* __restrict__ row,
                                              const int* __restrict__ col,
                                              int* __restrict__ T,
                                              int E, int NBLK, int NBUK)
{
    __shared__ int hc[MAXBUK], hr[MAXBUK];
    for (int b = threadIdx.x; b < NBUK; b += 256) { hc[b] = 0; hr[b] = 0; }
    __syncthreads();
    int base = blockIdx.x * EPB;
#pragma unroll
    for (int i = 0; i < 8; i++) {
        int e = base + i * 256 + threadIdx.x;
        if (e < E) {
            atomicAdd(&hc[col[e] >> BSH], 1);
            atomicAdd(&hr[row[e] >> BSH], 1);
        }
    }
    __syncthreads();
    int NT = NBUK * NBLK;
    for (int b = threadIdx.x; b < NBUK; b += 256) {
        T[b * NBLK + blockIdx.x]      = hc[b];
        T[NT + b * NBLK + blockIdx.x] = hr[b];
    }
}

// ---- exclusive scan: local pass + partials pass (fixup folded into readers) ----
__global__ __launch_bounds__(256) void k_scan_local(const int* __restrict__ in, int* __restrict__ out,
                                                    int* __restrict__ partials, int n)
{
    __shared__ int s[256];
    int base = blockIdx.x * 2048 + threadIdx.x * 8;
    int v[8]; int sum = 0;
#pragma unroll
    for (int i = 0; i < 8; i++) { v[i] = (base + i < n) ? in[base + i] : 0; sum += v[i]; }
    s[threadIdx.x] = sum;
    __syncthreads();
    for (int off = 1; off < 256; off <<= 1) {
        int t = (threadIdx.x >= off) ? s[threadIdx.x - off] : 0;
        __syncthreads();
        s[threadIdx.x] += t;
        __syncthreads();
    }
    int excl = s[threadIdx.x] - sum;
#pragma unroll
    for (int i = 0; i < 8; i++) { if (base + i < n) { out[base + i] = excl; excl += v[i]; } }
    if (threadIdx.x == 255) partials[blockIdx.x] = s[255];
}

// parallel exclusive scan of up to 1024 block partials (one block)
__global__ __launch_bounds__(1024) void k_scan_partials_par(int* __restrict__ partials, int nb)
{
    __shared__ int s[1024];
    int t = threadIdx.x;
    int v = (t < nb) ? partials[t] : 0;
    s[t] = v;
    __syncthreads();
    for (int off = 1; off < 1024; off <<= 1) {
        int u = (t >= off) ? s[t - off] : 0;
        __syncthreads();
        s[t] += u;
        __syncthreads();
    }
    if (t < nb) partials[t] = s[t] - v;
}

// ---- pass B: scatter edges to col-bucket regions (X) and row-bucket regions (Y) ----
// X entry: .x = (c_local<<25) | r   (needs N < 2^25), .y = val bits
// Y entry: .x = r_local, .y = |val| bits
__global__ __launch_bounds__(256) void k_scat(const int* __restrict__ row,
                                              const int* __restrict__ col,
                                              const float* __restrict__ val,
                                              const int* __restrict__ TS,
                                              const int* __restrict__ partials,
                                              int2* __restrict__ X, int2* __restrict__ Y,
                                              int E, int NBLK, int NBUK)
{
    __shared__ int oc[MAXBUK], orw[MAXBUK];
    int NT = NBUK * NBLK;
    for (int b = threadIdx.x; b < NBUK; b += 256) {
        oc[b]  = ts_g(TS, partials, b * NBLK + blockIdx.x);
        orw[b] = ts_g(TS, partials, NT + b * NBLK + blockIdx.x);
    }
    __syncthreads();
    int base = blockIdx.x * EPB;
#pragma unroll
    for (int i = 0; i < 8; i++) {
        int e = base + i * 256 + threadIdx.x;
        if (e < E) {
            int r = row[e], c = col[e];
            float v = val[e];
            int pc = atomicAdd(&oc[c >> BSH], 1);
            X[pc] = make_int2(((c & (NPB - 1)) << 25) | r, __float_as_int(v));
            int pr = atomicAdd(&orw[r >> BSH], 1);
            Y[pr - E] = make_int2(r & (NPB - 1), __float_as_int(fabsf(v)));
        }
    }
}

// ---- pass C (row): per-row-bucket reduction -> dinv, pv_self ----
__global__ __launch_bounds__(256) void k_rowstats(const int2* __restrict__ Y,
                                                  const int* __restrict__ TS,
                                                  const int* __restrict__ partials,
                                                  float* __restrict__ dinv,
                                                  float* __restrict__ pv_self,
                                                  int N, int E, int NBLK, int NBUK)
{
    __shared__ float fs[NPB];
    __shared__ int   cn[NPB];
    int t = threadIdx.x;
    if (t < NPB) { fs[t] = 0.f; cn[t] = 0; }
    __syncthreads();
    int NT = NBUK * NBLK;
    int buk = blockIdx.x;
    int s = ts_g(TS, partials, NT + buk * NBLK);
    int e = (buk == NBUK - 1) ? 2 * E : ts_g(TS, partials, NT + (buk + 1) * NBLK);
    for (int j = s + t; j < e; j += 256) {
        int2 y = Y[j - E];
        atomicAdd(&fs[y.x], __int_as_float(y.y));
        atomicAdd(&cn[y.x], 1);
    }
    __syncthreads();
    if (t < NPB) {
        int node = buk * NPB + t;
        if (node < N) {
            float as = fs[t];
            float c  = (float)cn[t];
            float am = as / fmaxf(c, 1.f);
            float deg = as + am;
            float di = deg > 0.f ? rsqrtf(deg) : 0.f;
            dinv[node]    = di;
            pv_self[node] = am * di * di;
        }
    }
}

// ---- pass C (col): per-col-bucket node ranking -> col_ptr, srt_rp (r,pv), x1 ----
__global__ __launch_bounds__(256) void k_colfinal(const int2* __restrict__ X,
                                                  const int* __restrict__ TS,
                                                  const int* __restrict__ partials,
                                                  const float* __restrict__ dinv,
                                                  const float* __restrict__ pv_self,
                                                  int* __restrict__ col_ptr,
                                                  int2* __restrict__ srt_rp,
                                                  float* __restrict__ x1,
                                                  int N, int E, int NBLK, int NBUK)
{
    __shared__ int   hist[NPB];
    __shared__ int   tmp[NPB];
    __shared__ int   rb[NPB];
    __shared__ float xs[NPB];
    __shared__ float dl[NPB];
    int t = threadIdx.x;
    int buk = blockIdx.x;
    int node = buk * NPB + t;
    if (t < NPB) {
        hist[t] = 0; xs[t] = 0.f;
        dl[t] = (node < N) ? dinv[node] : 0.f;
    }
    __syncthreads();
    int s  = ts_g(TS, partials, buk * NBLK);
    int e2 = (buk == NBUK - 1) ? E : ts_g(TS, partials, (buk + 1) * NBLK);
    for (int j = s + t; j < e2; j += 256) {
        unsigned xw = (unsigned)X[j].x;
        atomicAdd(&hist[xw >> 25], 1);
    }
    __syncthreads();
    if (t < NPB) tmp[t] = hist[t];
    __syncthreads();
    for (int off = 1; off < NPB; off <<= 1) {
        int u = (t >= off && t < NPB) ? tmp[t - off] : 0;
        __syncthreads();
        if (t < NPB) tmp[t] += u;
        __syncthreads();
    }
    if (t < NPB) {
        int excl = tmp[t] - hist[t];
        rb[t] = s + excl;
        if (node < N) col_ptr[node] = s + excl;
    }
    if (buk == NBUK - 1 && t == 0) col_ptr[N] = E;
    __syncthreads();
    for (int j = s + t; j < e2; j += 256) {
        int2 xx = X[j];
        unsigned xw = (unsigned)xx.x;
        int cl = xw >> 25;
        int r  = (int)(xw & 0x1FFFFFFu);
        float p = __int_as_float(xx.y) * dinv[r] * dl[cl];
        int pos = atomicAdd(&rb[cl], 1);
        srt_rp[pos] = make_int2(r, __float_as_int(p));
        atomicAdd(&xs[cl], p);
    }
    __syncthreads();
    if (t < NPB && node < N) x1[node] = pv_self[node] + xs[t];
}

// ---- conv2 propagate, broadcast form: one wave per node, 2 dims per lane.
// Output stored directly as bf16 (RNE).
__global__ __launch_bounds__(256) void k_prop2b(const int* __restrict__ col_ptr,
                                                const int2* __restrict__ srt_rp,
                                                const float* __restrict__ pv_self,
                                                const float* __restrict__ x1,
                                                const float* __restrict__ w1,
                                                const float* __restrict__ b1,
                                                unsigned int* __restrict__ p2b, int N)
{
    int node = blockIdx.x * 4 + (threadIdx.x >> 6);
    int lane = threadIdx.x & 63;
    if (node >= N) return;

    float2 w = *(const float2*)&w1[lane * 2];
    float2 b = *(const float2*)&b1[lane * 2];
    float ps  = pv_self[node];
    float x1n = x1[node];
    float acc0 = ps * leaky(fmaf(x1n, w.x, b.x));
    float acc1 = ps * leaky(fmaf(x1n, w.y, b.y));

    int s = col_ptr[node], e = col_ptr[node + 1];
    for (int base = s; base < e; base += 64) {
        int mc = min(64, e - base);
        float p = 0.f, sv = 0.f;
        if (lane < mc) {
            int2 rp = srt_rp[base + lane];
            p  = __int_as_float(rp.y);
            sv = x1[rp.x];
        }
        for (int k = 0; k < mc; ++k) {
            float pk = __shfl(p, k, 64);
            float sk = __shfl(sv, k, 64);
            acc0 += pk * leaky(fmaf(sk, w.x, b.x));
            acc1 += pk * leaky(fmaf(sk, w.y, b.y));
        }
    }

    p2b[(size_t)node * 64 + lane] = pk2bf(acc0, acc1);
}

// ---- conv3 gather propagate over bf16 z, one wave per node, 4-edge unroll ----
__global__ __launch_bounds__(256) void k_prop3_bf16(const int* __restrict__ col_ptr,
                                                    const int2* __restrict__ srt_rp,
                                                    const float* __restrict__ pv_self,
                                                    const unsigned int* __restrict__ zb,
                                                    const float* __restrict__ bias3,
                                                    float* __restrict__ out, int N)
{
    int node = blockIdx.x * 4 + (threadIdx.x >> 6);
    int lane = threadIdx.x & 63;
    if (node >= N) return;

    unsigned int us = zb[(size_t)node * 64 + lane];
    float ps = pv_self[node];
    float acc0 = ps * __uint_as_float(us << 16);
    float acc1 = ps * __uint_as_float(us & 0xFFFF0000u);

    int j = col_ptr[node], e = col_ptr[node + 1];
    for (; j + 3 < e; j += 4) {
        int2 rp0 = srt_rp[j];
        int2 rp1 = srt_rp[j + 1];
        int2 rp2 = srt_rp[j + 2];
        int2 rp3 = srt_rp[j + 3];
        unsigned int u0 = zb[(size_t)rp0.x * 64 + lane];
        unsigned int u1 = zb[(size_t)rp1.x * 64 + lane];
        unsigned int u2 = zb[(size_t)rp2.x * 64 + lane];
        unsigned int u3 = zb[(size_t)rp3.x * 64 + lane];
        float p0 = __int_as_float(rp0.y);
        float p1 = __int_as_float(rp1.y);
        float p2 = __int_as_float(rp2.y);
        float p3 = __int_as_float(rp3.y);
        acc0 += p0 * __uint_as_float(u0 << 16);
        acc1 += p0 * __uint_as_float(u0 & 0xFFFF0000u);
        acc0 += p1 * __uint_as_float(u1 << 16);
        acc1 += p1 * __uint_as_float(u1 & 0xFFFF0000u);
        acc0 += p2 * __uint_as_float(u2 << 16);
        acc1 += p2 * __uint_as_float(u2 & 0xFFFF0000u);
        acc0 += p3 * __uint_as_float(u3 << 16);
        acc1 += p3 * __uint_as_float(u3 & 0xFFFF0000u);
    }
    for (; j < e; ++j) {
        int2 rp = srt_rp[j];
        unsigned int u = zb[(size_t)rp.x * 64 + lane];
        float p = __int_as_float(rp.y);
        acc0 += p * __uint_as_float(u << 16);
        acc1 += p * __uint_as_float(u & 0xFFFF0000u);
    }

    float2 b = *(const float2*)&bias3[lane * 2];
    float2 o = make_float2(leaky(acc0 + b.x), leaky(acc1 + b.y));
    *(float2*)&out[(size_t)node * D1 + lane * 2] = o;
}

// ---- one-shot weight pre-convert to fragment-layout bf16 ----
// w2f[((k>>3)*256 + m)*8 + (k&7)] = bf16(w2[m][k])   (m<256, k<128)
// w3f[((k>>3)*128 + m)*8 + (k&7)] = bf16(w3[m][k])   (m<128, k<256)
__global__ __launch_bounds__(256) void k_cvtw(const float* __restrict__ w2,
                                              const float* __restrict__ w3,
                                              unsigned short* __restrict__ w2f,
                                              unsigned short* __restrict__ w3f)
{
    int i = blockIdx.x * 256 + threadIdx.x;   // 0 .. 32767 (both tables are 32768 elems)
    {
        int m = i >> 7, k = i & 127;
        w2f[(((k >> 3) * 256 + m) << 3) + (k & 7)] = f2bf(w2[i]);
    }
    {
        int m = i >> 8, k = i & 255;
        w3f[(((k >> 3) * 128 + m) << 3) + (k & 7)] = f2bf(w3[i]);
    }
}

// ---- fused MFMA GEMM chain v2 (barrier-light, conflict-free LDS) ----
// Per 64-node block:
//   stage A = p2 tile into LDS [kblk][node][8] (16 KB), 1 barrier
//   phase 1 (no barriers): acc1 = mfma(w2-frag from GLOBAL w2f, p2-frag from LDS)
//            -> D[w2col][node] (operand swap: bitwise-identical products/order)
//   epilogue 1: H^T into LDS [kblk=w2col/8][node][8] via packed ds_write_b64, 1 barrier
//   phase 2 (no barriers): acc2 = mfma(w3-frag from GLOBAL w3f, H-frag from LDS)
//   epilogue 2: packed ushort4 stores to zb (+b3)
// zb may alias p2b: block fully consumes its own 64 p2b rows before writing the
// same-extent zb rows; no cross-block row sharing.
__global__ __launch_bounds__(256, 3) void k_gemm_fused2(const unsigned int* __restrict__ p2b,
                                                        const unsigned short* __restrict__ w2f,
                                                        const float* __restrict__ b2,
                                                        const float* __restrict__ bias2,
                                                        const unsigned short* __restrict__ w3f,
                                                        const float* __restrict__ b3,
                                                        const float* __restrict__ x1,
                                                        unsigned short* __restrict__ zb,
                                                        int N)
{
    typedef __attribute__((ext_vector_type(8))) short short8v;
    typedef __attribute__((ext_vector_type(4))) float f32x4;

    __shared__ unsigned short Ak[16 * 64 * 8];   // p2 tile, [kblk][node][8], 16 KB
    __shared__ unsigned short H [32 * 64 * 8];   // H^T tile, [w2col/8][node][8], 32 KB

    const int t = threadIdx.x;
    const int n_base = blockIdx.x * 64;
    const int l  = t & 63, wid = t >> 6;
    const int lr = l & 15, lk = l >> 4;

    // ---- stage A (one barrier) ----
    {
        const int node = t & 63, kb0 = t >> 6;
        const bool ok = (n_base + node) < N;
        const unsigned int* src = p2b + (size_t)(n_base + node) * 64;
#pragma unroll
        for (int kk = 0; kk < 4; kk++) {
            int kblk = kk * 4 + kb0;
            uint4 v = ok ? *(const uint4*)(src + kblk * 4) : make_uint4(0u, 0u, 0u, 0u);
            *(uint4*)&Ak[(kblk * 64 + node) * 8] = v;
        }
    }
    __syncthreads();

    // ---- phase 1: wave owns w2cols [wid*64, wid*64+64) ----
    f32x4 acc1[4][4] = {};
#pragma unroll
    for (int k0 = 0; k0 < D1; k0 += 32) {
        short8v af[4], bf[4];
#pragma unroll
        for (int i = 0; i < 4; i++)
            af[i] = *(const short8v*)&w2f[((((k0 >> 3) + lk) * 256) + wid * 64 + i * 16 + lr) * 8];
#pragma unroll
        for (int j = 0; j < 4; j++)
            bf[j] = *(const short8v*)&Ak[(((k0 >> 3) + lk) * 64 + j * 16 + lr) * 8];
#pragma unroll
        for (int i = 0; i < 4; i++)
#pragma unroll
            for (int j = 0; j < 4; j++)
                acc1[i][j] = __builtin_amdgcn_mfma_f32_16x16x32_bf16(af[i], bf[j], acc1[i][j], 0, 0, 0);
    }

    // ---- epilogue 1 -> H (packed b64 writes; k-quads are lane-local) ----
    {
        float xv[4];
#pragma unroll
        for (int j = 0; j < 4; j++) {
            int node = n_base + j * 16 + lr;
            xv[j] = (node < N) ? x1[node] : 0.f;
        }
#pragma unroll
        for (int i = 0; i < 4; i++) {
            const int c0 = wid * 64 + i * 16 + lk * 4;   // 4 consecutive w2cols
            float4 bq  = *(const float4*)&b2[c0];
            float4 biq = *(const float4*)&bias2[c0];
            const int kblk = wid * 8 + i * 2 + (lk >> 1);
#pragma unroll
            for (int j = 0; j < 4; j++) {
                float v0 = leaky(acc1[i][j][0] + xv[j] * bq.x + biq.x);
                float v1 = leaky(acc1[i][j][1] + xv[j] * bq.y + biq.y);
                float v2 = leaky(acc1[i][j][2] + xv[j] * bq.z + biq.z);
                float v3 = leaky(acc1[i][j][3] + xv[j] * bq.w + biq.w);
                uint2 pk = make_uint2(pk2bf(v0, v1), pk2bf(v2, v3));
                *(uint2*)&H[(kblk * 64 + j * 16 + lr) * 8 + (lk & 1) * 4] = pk;
            }
        }
    }
    __syncthreads();

    // ---- phase 2: wave owns w3cols [wid*32, wid*32+32) ----
    f32x4 acc2[2][4] = {};
#pragma unroll
    for (int k0 = 0; k0 < D2; k0 += 32) {
        short8v af[2], bf[4];
#pragma unroll
        for (int i = 0; i < 2; i++)
            af[i] = *(const short8v*)&w3f[((((k0 >> 3) + lk) * 128) + wid * 32 + i * 16 + lr) * 8];
#pragma unroll
        for (int j = 0; j < 4; j++)
            bf[j] = *(const short8v*)&H[(((k0 >> 3) + lk) * 64 + j * 16 + lr) * 8];
#pragma unroll
        for (int i = 0; i < 2; i++)
#pragma unroll
            for (int j = 0; j < 4; j++)
                acc2[i][j] = __builtin_amdgcn_mfma_f32_16x16x32_bf16(af[i], bf[j], acc2[i][j], 0, 0, 0);
    }

    // ---- epilogue 2 -> zb (packed ushort4 stores) ----
#pragma unroll
    for (int i = 0; i < 2; i++) {
        const int m0 = wid * 32 + i * 16 + lk * 4;   // 4 consecutive z-cols
        float4 bq = *(const float4*)&b3[m0];
#pragma unroll
        for (int j = 0; j < 4; j++) {
            int node = n_base + j * 16 + lr;
            if (node < N) {
                ushort4 s4;
                s4.x = f2bf(acc2[i][j][0] + bq.x);
                s4.y = f2bf(acc2[i][j][1] + bq.y);
                s4.z = f2bf(acc2[i][j][2] + bq.z);
                s4.w = f2bf(acc2[i][j][3] + bq.w);
                *(ushort4*)&zb[(size_t)node * D1 + m0] = s4;
            }
        }
    }
}

extern "C" void kernel_launch(void* const* d_in, const int* in_sizes, int n_in,
                              void* d_out, int out_size, void* d_ws, size_t ws_size,
                              hipStream_t stream)
{
    const int* ei       = (const int*)d_in[0];     // (2,E) int32
    const float* val    = (const float*)d_in[1];   // (E,)
    const float* w1     = (const float*)d_in[3];   // (128,1)
    const float* b1     = (const float*)d_in[4];   // (128,)
    const float* w2     = (const float*)d_in[5];   // (256,128)
    const float* b2     = (const float*)d_in[6];   // (256,)
    const float* bias2  = (const float*)d_in[7];   // (256,)
    const float* w3     = (const float*)d_in[8];   // (128,256)
    const float* b3     = (const float*)d_in[9];   // (128,)
    const float* bias3  = (const float*)d_in[10];  // (128,)
    float* out = (float*)d_out;

    const int E = in_sizes[1];
    const int N = out_size / D1;
    const int* row = ei;
    const int* col = ei + E;

    const int NBLK = (E + EPB - 1) / EPB;          // edge blocks (782 @ E=1.6M)
    const int NBUK = (N + NPB - 1) >> BSH;         // node buckets (782 @ N=100K)
    const int NT   = NBUK * NBLK;

    // workspace layout
    float* dinv    = (float*)d_ws;                                   // N
    float* pv_self = dinv + N;                                       // N
    float* x1      = pv_self + N;                                    // N
    int*   col_ptr = (int*)(x1 + N);                                 // N+8
    int*   partials= col_ptr + N + 8;                                // 1024
    int2*  srt_rp  = (int2*)(partials + 1024);                       // E int2
    unsigned int* p2b = (unsigned int*)(srt_rp + (size_t)E);         // N*64 uints (bf16 p2)
    int*   TS      = (int*)(p2b + (size_t)N * 64);                   // 2*NT scanned table
    int*   T       = TS + (size_t)2 * NT;                            // 2*NT raw histograms
    int2*  Y       = (int2*)(T + (size_t)2 * NT);                    // E (row-bucketed edges)
    unsigned short* w2f = (unsigned short*)(Y + (size_t)E);          // 32768 bf16 (frag layout)
    unsigned short* w3f = w2f + 32768;                               // 32768 bf16 (frag layout)
    // aliases:
    int2* X = (int2*)p2b;                    // E entries; dead before k_prop2b writes p2b (E*8 <= N*256)
    unsigned short* zb = (unsigned short*)p2b;  // fused-GEMM z out; per-block self-alias with p2b is safe

    const int B = 256;
    const int n2 = 2 * NT;
    const int scan_blocks = (n2 + 2047) / 2048;    // 598 @ default sizes (<= 1024)

    // bucket-sort pipeline: LDS atomics only, zero global atomics, no memsets
    k_hist<<<NBLK, B, 0, stream>>>(row, col, T, E, NBLK, NBUK);
    k_scan_local<<<scan_blocks, 256, 0, stream>>>(T, TS, partials, n2);
    k_scan_partials_par<<<1, 1024, 0, stream>>>(partials, scan_blocks);
    k_scat<<<NBLK, B, 0, stream>>>(row, col, val, TS, partials, X, Y, E, NBLK, NBUK);
    k_rowstats<<<NBUK, B, 0, stream>>>(Y, TS, partials, dinv, pv_self, N, E, NBLK, NBUK);
    k_colfinal<<<NBUK, B, 0, stream>>>(X, TS, partials, dinv, pv_self, col_ptr, srt_rp, x1, N, E, NBLK, NBUK);

    // weights -> fragment-layout bf16 (once)
    k_cvtw<<<128, 256, 0, stream>>>(w2, w3, w2f, w3f);

    // conv2 propagate -> bf16 p2, then fused MFMA chain p2 -> H(LDS) -> z
    k_prop2b<<<(N + 3) / 4, 256, 0, stream>>>(col_ptr, srt_rp, pv_self, x1, w1, b1, p2b, N);
    k_gemm_fused2<<<(N + 63) / 64, 256, 0, stream>>>(p2b, w2f, b2, bias2, w3f, b3, x1, zb, N);

    // conv3 gather propagate + fused bias3/leaky
    k_prop3_bf16<<<(N + 3) / 4, 256, 0, stream>>>(col_ptr, srt_rp, pv_self, (const unsigned int*)zb, bias3, out, N);
}